// Round 3
// baseline (464.825 us; speedup 1.0000x reference)
//
#include <hip/hip_runtime.h>
#include <hip/hip_bf16.h>
#include <cstdint>

#define N_NODES 50000
#define N_EDGES 800000
#define C128 128

// ---------------------------------------------------------------------------
// init / graph preprocessing
// ---------------------------------------------------------------------------

__global__ void k_zero(int* __restrict__ a, int* __restrict__ b, int n) {
    int i = blockIdx.x * blockDim.x + threadIdx.x;
    if (i < n) { a[i] = 0; b[i] = 0; }
}

__device__ __forceinline__ int clamp_node(int v) {
    return v < 0 ? 0 : (v >= N_NODES ? N_NODES - 1 : v);
}

__global__ void k_count(const int* __restrict__ ei, int* __restrict__ counts) {
    int e = blockIdx.x * blockDim.x + threadIdx.x;
    if (e < N_EDGES) {
        int dst = clamp_node(ei[N_EDGES + e]);
        atomicAdd(&counts[dst], 1);
    }
}

__global__ void k_dinv(const int* __restrict__ counts, float* __restrict__ dinv) {
    int i = blockIdx.x * blockDim.x + threadIdx.x;
    if (i < N_NODES) {
        dinv[i] = rsqrtf((float)counts[i] + 1.0f);
    }
}

// single-block exclusive scan over counts -> offsets[N_NODES+1]
__global__ __launch_bounds__(1024) void k_scan(const int* __restrict__ counts,
                                               int* __restrict__ offsets) {
    __shared__ int sums[1024];
    const int tid = threadIdx.x;
    const int chunk = (N_NODES + 1023) / 1024;  // 49
    const int start = tid * chunk;
    const int end = min(start + chunk, N_NODES);
    int s = 0;
    for (int i = start; i < end; ++i) s += counts[i];
    sums[tid] = s;
    __syncthreads();
    for (int off = 1; off < 1024; off <<= 1) {
        int v = (tid >= off) ? sums[tid - off] : 0;
        __syncthreads();
        sums[tid] += v;
        __syncthreads();
    }
    int run = (tid == 0) ? 0 : sums[tid - 1];
    for (int i = start; i < end; ++i) {
        offsets[i] = run;
        run += counts[i];
    }
    if (tid == 1023) offsets[N_NODES] = run;  // == N_EDGES
}

__global__ void k_fill(const int* __restrict__ ei, const int* __restrict__ offsets,
                       int* __restrict__ cursor, int* __restrict__ csr) {
    int e = blockIdx.x * blockDim.x + threadIdx.x;
    if (e < N_EDGES) {
        int src = clamp_node(ei[e]);
        int dst = clamp_node(ei[N_EDGES + e]);
        int pos = atomicAdd(&cursor[dst], 1);
        int slot = offsets[dst] + pos;
        if (slot < N_EDGES) csr[slot] = src;
    }
}

// ---------------------------------------------------------------------------
// Propagation: out[i] = dinv[i]*( sum_{s in N(i)} dinv[s]*in[s] + dinv[i]*in[i] ) (+bias)(relu)
// One wave per node, 128 channels as float2 per lane.
// ---------------------------------------------------------------------------

template <bool HAS_BIAS, bool RELU>
__global__ __launch_bounds__(256) void k_prop(const float* __restrict__ in,
                                              float* __restrict__ out,
                                              const float* __restrict__ dinv,
                                              const int* __restrict__ offsets,
                                              const int* __restrict__ csr,
                                              const float* __restrict__ bias) {
    const int wave = threadIdx.x >> 6;
    const int lane = threadIdx.x & 63;
    const int node = blockIdx.x * 4 + wave;
    if (node >= N_NODES) return;

    const float di = dinv[node];
    float2 sv = reinterpret_cast<const float2*>(in + (size_t)node * C128)[lane];
    float acc0 = di * sv.x;
    float acc1 = di * sv.y;

    int e = offsets[node];
    const int eend = offsets[node + 1];
    for (; e + 4 <= eend; e += 4) {
        int s0 = csr[e + 0], s1 = csr[e + 1], s2 = csr[e + 2], s3 = csr[e + 3];
        float w0 = dinv[s0], w1 = dinv[s1], w2 = dinv[s2], w3 = dinv[s3];
        float2 v0 = reinterpret_cast<const float2*>(in + (size_t)s0 * C128)[lane];
        float2 v1 = reinterpret_cast<const float2*>(in + (size_t)s1 * C128)[lane];
        float2 v2 = reinterpret_cast<const float2*>(in + (size_t)s2 * C128)[lane];
        float2 v3 = reinterpret_cast<const float2*>(in + (size_t)s3 * C128)[lane];
        acc0 = fmaf(w0, v0.x, acc0); acc1 = fmaf(w0, v0.y, acc1);
        acc0 = fmaf(w1, v1.x, acc0); acc1 = fmaf(w1, v1.y, acc1);
        acc0 = fmaf(w2, v2.x, acc0); acc1 = fmaf(w2, v2.y, acc1);
        acc0 = fmaf(w3, v3.x, acc0); acc1 = fmaf(w3, v3.y, acc1);
    }
    for (; e < eend; ++e) {
        int s = csr[e];
        float w = dinv[s];
        float2 v = reinterpret_cast<const float2*>(in + (size_t)s * C128)[lane];
        acc0 = fmaf(w, v.x, acc0);
        acc1 = fmaf(w, v.y, acc1);
    }

    float o0 = di * acc0;
    float o1 = di * acc1;
    if (HAS_BIAS) {
        o0 += bias[2 * lane + 0];
        o1 += bias[2 * lane + 1];
    }
    if (RELU) {
        o0 = fmaxf(o0, 0.0f);
        o1 = fmaxf(o1, 0.0f);
    }
    reinterpret_cast<float2*>(out + (size_t)node * C128)[lane] = make_float2(o0, o1);
}

// ---------------------------------------------------------------------------
// f32 tiled GEMM, output width fixed at 128 (one tile), K multiple of 16.
// C[M,128] (ldc) = act( A[M,K] (lda) @ B[K,128] (ldb) + bias ) [+ C if ACCUM]
// tile 128(M)x128(N), BK=16, 256 threads, 8x8 microtile.
// ACT: 0 = none, 1 = relu, 2 = elu
// ---------------------------------------------------------------------------

template <int ACT, bool ACCUM>
__global__ __launch_bounds__(256) void k_gemm(const float* __restrict__ A, int lda,
                                              const float* __restrict__ B, int ldb,
                                              const float* __restrict__ bias,
                                              float* __restrict__ C, int ldc,
                                              int M, int K) {
    __shared__ float As[16][128];
    __shared__ float Bs[16][128];

    const int tid = threadIdx.x;
    const int tx = tid & 15;
    const int ty = tid >> 4;
    const int row0 = ty * 4;
    const int col0 = tx * 4;
    const int m_base = blockIdx.x * 128;

    float acc[8][8] = {};

    const int a_row = tid >> 2;         // 0..63
    const int a_col = (tid & 3) * 4;    // 0,4,8,12
    const int b_row = tid >> 5;         // 0..7
    const int b_col = (tid & 31) * 4;   // 0..124

    for (int k0 = 0; k0 < K; k0 += 16) {
        int gr0 = m_base + a_row;
        int gr1 = m_base + a_row + 64;
        if (gr0 >= M) gr0 = M - 1;
        if (gr1 >= M) gr1 = M - 1;
        float4 av0 = *reinterpret_cast<const float4*>(A + (size_t)gr0 * lda + k0 + a_col);
        float4 av1 = *reinterpret_cast<const float4*>(A + (size_t)gr1 * lda + k0 + a_col);
        float4 bv0 = *reinterpret_cast<const float4*>(B + (size_t)(k0 + b_row) * ldb + b_col);
        float4 bv1 = *reinterpret_cast<const float4*>(B + (size_t)(k0 + b_row + 8) * ldb + b_col);

        As[a_col + 0][a_row] = av0.x;
        As[a_col + 1][a_row] = av0.y;
        As[a_col + 2][a_row] = av0.z;
        As[a_col + 3][a_row] = av0.w;
        As[a_col + 0][a_row + 64] = av1.x;
        As[a_col + 1][a_row + 64] = av1.y;
        As[a_col + 2][a_row + 64] = av1.z;
        As[a_col + 3][a_row + 64] = av1.w;
        *reinterpret_cast<float4*>(&Bs[b_row][b_col]) = bv0;
        *reinterpret_cast<float4*>(&Bs[b_row + 8][b_col]) = bv1;
        __syncthreads();

#pragma unroll
        for (int k = 0; k < 16; ++k) {
            float4 a0 = *reinterpret_cast<const float4*>(&As[k][row0]);
            float4 a1 = *reinterpret_cast<const float4*>(&As[k][row0 + 64]);
            float4 b0 = *reinterpret_cast<const float4*>(&Bs[k][col0]);
            float4 b1 = *reinterpret_cast<const float4*>(&Bs[k][col0 + 64]);
            float ar[8] = {a0.x, a0.y, a0.z, a0.w, a1.x, a1.y, a1.z, a1.w};
            float br[8] = {b0.x, b0.y, b0.z, b0.w, b1.x, b1.y, b1.z, b1.w};
#pragma unroll
            for (int i = 0; i < 8; ++i)
#pragma unroll
                for (int j = 0; j < 8; ++j)
                    acc[i][j] = fmaf(ar[i], br[j], acc[i][j]);
        }
        __syncthreads();
    }

#pragma unroll
    for (int i = 0; i < 8; ++i) {
        int r = m_base + row0 + (i < 4 ? i : 60 + i);  // rows row0..+3 and row0+64..+67
        if (r >= M) continue;
#pragma unroll
        for (int jh = 0; jh < 2; ++jh) {
            int c = col0 + jh * 64;
            float4 v;
            v.x = acc[i][jh * 4 + 0];
            v.y = acc[i][jh * 4 + 1];
            v.z = acc[i][jh * 4 + 2];
            v.w = acc[i][jh * 4 + 3];
            float* cp = C + (size_t)r * ldc + c;
            if (ACCUM) {
                float4 old = *reinterpret_cast<const float4*>(cp);
                v.x += old.x; v.y += old.y; v.z += old.z; v.w += old.w;
            }
            if (bias != nullptr) {
                v.x += bias[c + 0];
                v.y += bias[c + 1];
                v.z += bias[c + 2];
                v.w += bias[c + 3];
            }
            if (ACT == 1) {
                v.x = fmaxf(v.x, 0.0f); v.y = fmaxf(v.y, 0.0f);
                v.z = fmaxf(v.z, 0.0f); v.w = fmaxf(v.w, 0.0f);
            } else if (ACT == 2) {
                v.x = v.x > 0.0f ? v.x : (expf(v.x) - 1.0f);
                v.y = v.y > 0.0f ? v.y : (expf(v.y) - 1.0f);
                v.z = v.z > 0.0f ? v.z : (expf(v.z) - 1.0f);
                v.w = v.w > 0.0f ? v.w : (expf(v.w) - 1.0f);
            }
            *reinterpret_cast<float4*>(cp) = v;
        }
    }
}

// ---------------------------------------------------------------------------
// launch
// ---------------------------------------------------------------------------

extern "C" void kernel_launch(void* const* d_in, const int* in_sizes, int n_in,
                              void* d_out, int out_size, void* d_ws, size_t ws_size,
                              hipStream_t stream) {
    const float* x    = (const float*)d_in[0];
    const int*   ei   = (const int*)d_in[1];   // int64 in reference -> int32 from harness
    const float* W1   = (const float*)d_in[2]; // [128,256]
    const float* b1   = (const float*)d_in[3]; // [256]
    const float* W2   = (const float*)d_in[4]; // [256,128]
    const float* b2   = (const float*)d_in[5]; // [128]
    const float* fcW1 = (const float*)d_in[6]; // [128,128]
    const float* fcb1 = (const float*)d_in[7];
    const float* fcW2 = (const float*)d_in[8]; // [128,128]
    const float* fcb2 = (const float*)d_in[9];
    float* out        = (float*)d_out;         // [N,128], also used as ping-pong scratch

    char* ws = (char*)d_ws;
    size_t off = 0;
    auto alloc = [&](size_t bytes) {
        void* p = ws + off;
        off += (bytes + 255) & ~(size_t)255;
        return p;
    };
    int*   counts  = (int*)alloc(N_NODES * sizeof(int));
    int*   cursor  = (int*)alloc(N_NODES * sizeof(int));
    int*   offsets = (int*)alloc((N_NODES + 1) * sizeof(int));
    int*   csr     = (int*)alloc(N_EDGES * sizeof(int));
    float* dinv    = (float*)alloc(N_NODES * sizeof(float));
    float* Hh      = (float*)alloc((size_t)N_NODES * 128 * sizeof(float)); // half of h
    float* Q       = (float*)alloc((size_t)N_NODES * 128 * sizeof(float)); // hw / p
    (void)ws_size; (void)n_in; (void)in_sizes; (void)out_size;

    // graph preprocessing
    k_zero<<<(N_NODES + 255) / 256, 256, 0, stream>>>(counts, cursor, N_NODES);
    k_count<<<(N_EDGES + 255) / 256, 256, 0, stream>>>(ei, counts);
    k_dinv<<<(N_NODES + 255) / 256, 256, 0, stream>>>(counts, dinv);
    k_scan<<<1, 1024, 0, stream>>>(counts, offsets);
    k_fill<<<(N_EDGES + 255) / 256, 256, 0, stream>>>(ei, offsets, cursor, csr);

    const int prop_grid = (N_NODES + 3) / 4;
    const int gm = (N_NODES + 127) / 128;  // 391

    // layer 1 propagate on 128-ch side: agg = prop(x)  -> out (scratch)
    k_prop<false, false><<<prop_grid, 256, 0, stream>>>(x, out, dinv, offsets, csr, nullptr);

    // h = relu(agg @ W1 + b1) in two column-halves; hw = h @ W2 accumulated
    // h0 = relu(agg @ W1[:, :128] + b1[:128])
    k_gemm<1, false><<<gm, 256, 0, stream>>>(out, 128, W1, 256, b1, Hh, 128, N_NODES, 128);
    // Q = h0 @ W2[:128, :]
    k_gemm<0, false><<<gm, 256, 0, stream>>>(Hh, 128, W2, 128, nullptr, Q, 128, N_NODES, 128);
    // h1 = relu(agg @ W1[:, 128:] + b1[128:])
    k_gemm<1, false><<<gm, 256, 0, stream>>>(out, 128, W1 + 128, 256, b1 + 128, Hh, 128, N_NODES, 128);
    // Q += h1 @ W2[128:, :]
    k_gemm<0, true><<<gm, 256, 0, stream>>>(Hh, 128, W2 + 128 * 128, 128, nullptr, Q, 128, N_NODES, 128);

    // layer 2 propagate (post-GEMM side): z = relu(prop(Q) + b2) -> out (scratch)
    k_prop<true, true><<<prop_grid, 256, 0, stream>>>(Q, out, dinv, offsets, csr, b2);

    // head: p = elu(z @ fcW1 + fcb1) -> Q ; out = p @ fcW2 + fcb2
    k_gemm<2, false><<<gm, 256, 0, stream>>>(out, 128, fcW1, 128, fcb1, Q, 128, N_NODES, 128);
    k_gemm<0, false><<<gm, 256, 0, stream>>>(Q, 128, fcW2, 128, fcb2, out, 128, N_NODES, 128);
}

// Round 4
// 384.522 us; speedup vs baseline: 1.2088x; 1.2088x over previous
//
#include <hip/hip_runtime.h>
#include <hip/hip_bf16.h>
#include <cstdint>

#define N_NODES 50000
#define N_EDGES 800000
#define C128 128
#define SCAN_BLOCKS ((N_NODES + 255) / 256)   // 196

// ---------------------------------------------------------------------------
// init / graph preprocessing
// ---------------------------------------------------------------------------

__global__ void k_zero(int* __restrict__ a, int* __restrict__ b, int n) {
    int i = blockIdx.x * blockDim.x + threadIdx.x;
    if (i < n) { a[i] = 0; b[i] = 0; }
}

__device__ __forceinline__ int clamp_node(int v) {
    return v < 0 ? 0 : (v >= N_NODES ? N_NODES - 1 : v);
}

__global__ void k_count(const int* __restrict__ ei, int* __restrict__ counts) {
    int e = blockIdx.x * blockDim.x + threadIdx.x;
    if (e < N_EDGES) {
        int dst = clamp_node(ei[N_EDGES + e]);
        atomicAdd(&counts[dst], 1);
    }
}

__global__ void k_dinv(const int* __restrict__ counts, float* __restrict__ dinv) {
    int i = blockIdx.x * blockDim.x + threadIdx.x;
    if (i < N_NODES) {
        dinv[i] = rsqrtf((float)counts[i] + 1.0f);
    }
}

// hierarchical exclusive scan: per-block inclusive scan + block sums
__global__ __launch_bounds__(256) void k_scan1(const int* __restrict__ counts,
                                               int* __restrict__ part,
                                               int* __restrict__ bsum) {
    __shared__ int s[256];
    const int tid = threadIdx.x;
    const int i = blockIdx.x * 256 + tid;
    int v = (i < N_NODES) ? counts[i] : 0;
    s[tid] = v;
    __syncthreads();
    for (int off = 1; off < 256; off <<= 1) {
        int t = (tid >= off) ? s[tid - off] : 0;
        __syncthreads();
        s[tid] += t;
        __syncthreads();
    }
    if (i < N_NODES) part[i] = s[tid];        // inclusive scan within block
    if (tid == 255) bsum[blockIdx.x] = s[255];
}

__global__ __launch_bounds__(256) void k_scan2(const int* __restrict__ bsum,
                                               int* __restrict__ boff) {
    __shared__ int s[256];
    const int tid = threadIdx.x;
    int v = (tid < SCAN_BLOCKS) ? bsum[tid] : 0;
    s[tid] = v;
    __syncthreads();
    for (int off = 1; off < 256; off <<= 1) {
        int t = (tid >= off) ? s[tid - off] : 0;
        __syncthreads();
        s[tid] += t;
        __syncthreads();
    }
    if (tid < SCAN_BLOCKS) boff[tid] = s[tid] - v;  // exclusive block offset
}

__global__ __launch_bounds__(256) void k_scan3(const int* __restrict__ part,
                                               const int* __restrict__ counts,
                                               const int* __restrict__ boff,
                                               int* __restrict__ offsets) {
    const int i = blockIdx.x * 256 + threadIdx.x;
    if (i < N_NODES) offsets[i] = part[i] - counts[i] + boff[blockIdx.x];
    if (i == 0) offsets[N_NODES] = N_EDGES;
}

__global__ void k_fill(const int* __restrict__ ei, const int* __restrict__ offsets,
                       int* __restrict__ cursor, int* __restrict__ csr) {
    int e = blockIdx.x * blockDim.x + threadIdx.x;
    if (e < N_EDGES) {
        int src = clamp_node(ei[e]);
        int dst = clamp_node(ei[N_EDGES + e]);
        int pos = atomicAdd(&cursor[dst], 1);
        int slot = offsets[dst] + pos;
        if (slot < N_EDGES) csr[slot] = src;
    }
}

// ---------------------------------------------------------------------------
// Propagation: out[i] = dinv[i]*( sum_{s in N(i)} dinv[s]*in[s] + dinv[i]*in[i] ) (+bias)(relu)
// One wave per node, 128 channels as float2 per lane.
// ---------------------------------------------------------------------------

template <bool HAS_BIAS, bool RELU>
__global__ __launch_bounds__(256) void k_prop(const float* __restrict__ in,
                                              float* __restrict__ out,
                                              const float* __restrict__ dinv,
                                              const int* __restrict__ offsets,
                                              const int* __restrict__ csr,
                                              const float* __restrict__ bias) {
    const int wave = threadIdx.x >> 6;
    const int lane = threadIdx.x & 63;
    const int node = blockIdx.x * 4 + wave;
    if (node >= N_NODES) return;

    const float di = dinv[node];
    float2 sv = reinterpret_cast<const float2*>(in + (size_t)node * C128)[lane];
    float acc0 = di * sv.x;
    float acc1 = di * sv.y;

    int e = offsets[node];
    const int eend = offsets[node + 1];
    for (; e + 4 <= eend; e += 4) {
        int s0 = csr[e + 0], s1 = csr[e + 1], s2 = csr[e + 2], s3 = csr[e + 3];
        float w0 = dinv[s0], w1 = dinv[s1], w2 = dinv[s2], w3 = dinv[s3];
        float2 v0 = reinterpret_cast<const float2*>(in + (size_t)s0 * C128)[lane];
        float2 v1 = reinterpret_cast<const float2*>(in + (size_t)s1 * C128)[lane];
        float2 v2 = reinterpret_cast<const float2*>(in + (size_t)s2 * C128)[lane];
        float2 v3 = reinterpret_cast<const float2*>(in + (size_t)s3 * C128)[lane];
        acc0 = fmaf(w0, v0.x, acc0); acc1 = fmaf(w0, v0.y, acc1);
        acc0 = fmaf(w1, v1.x, acc0); acc1 = fmaf(w1, v1.y, acc1);
        acc0 = fmaf(w2, v2.x, acc0); acc1 = fmaf(w2, v2.y, acc1);
        acc0 = fmaf(w3, v3.x, acc0); acc1 = fmaf(w3, v3.y, acc1);
    }
    for (; e < eend; ++e) {
        int s = csr[e];
        float w = dinv[s];
        float2 v = reinterpret_cast<const float2*>(in + (size_t)s * C128)[lane];
        acc0 = fmaf(w, v.x, acc0);
        acc1 = fmaf(w, v.y, acc1);
    }

    float o0 = di * acc0;
    float o1 = di * acc1;
    if (HAS_BIAS) {
        o0 += bias[2 * lane + 0];
        o1 += bias[2 * lane + 1];
    }
    if (RELU) {
        o0 = fmaxf(o0, 0.0f);
        o1 = fmaxf(o1, 0.0f);
    }
    reinterpret_cast<float2*>(out + (size_t)node * C128)[lane] = make_float2(o0, o1);
}

// ---------------------------------------------------------------------------
// Fused 2-GEMM chain per 128-row block:
//   for half in [0,NHALF): h = ACT1(A@W1[:,half*128:+128] + b1[half*128:+128])
//                          accQ += h @ W2[half*128:+128, :]
//   C = accQ (+ b2 if FINAL_BIAS)
// A [M,128], W1 [128, 128*NHALF], W2 [128*NHALF, 128], C [M,128].
// In-place C==A is safe: each block reads only its own rows, all reads before writes.
// ACT1: 1 = relu, 2 = elu
// ---------------------------------------------------------------------------

template <int NHALF, int ACT1, bool FINAL_BIAS>
__global__ __launch_bounds__(256, 2) void k_fused(const float* __restrict__ A,
                                                  const float* __restrict__ W1,
                                                  const float* __restrict__ b1v,
                                                  const float* __restrict__ W2,
                                                  const float* __restrict__ b2v,
                                                  float* __restrict__ C,
                                                  int M) {
    __shared__ float Hs[128][132];   // h tile, stored TRANSPOSED: Hs[col][row]
    __shared__ float Bs[16][128];    // W staging
    float* HsFlat = &Hs[0][0];       // first 8 KB aliased as As[16][128] in phase 1

    const int tid = threadIdx.x;
    const int tx = tid & 15;
    const int ty = tid >> 4;
    const int row0 = ty * 4;
    const int col0 = tx * 4;
    const int m_base = blockIdx.x * 128;

    const int a_row = tid >> 2;       // 0..63
    const int a_col = (tid & 3) * 4;  // 0,4,8,12
    const int b_row = tid >> 5;       // 0..7
    const int b_col = (tid & 31) * 4; // 0..124

    const int W1ld = 128 * NHALF;

    float accQ[8][8] = {};

    for (int half = 0; half < NHALF; ++half) {
        // ---------------- phase 1: accH = A @ W1half ----------------
        float accH[8][8] = {};
        for (int k0 = 0; k0 < 128; k0 += 16) {
            int gr0 = m_base + a_row;
            int gr1 = m_base + a_row + 64;
            if (gr0 >= M) gr0 = M - 1;
            if (gr1 >= M) gr1 = M - 1;
            float4 av0 = *reinterpret_cast<const float4*>(A + (size_t)gr0 * 128 + k0 + a_col);
            float4 av1 = *reinterpret_cast<const float4*>(A + (size_t)gr1 * 128 + k0 + a_col);
            float4 bv0 = *reinterpret_cast<const float4*>(W1 + (size_t)(k0 + b_row) * W1ld + half * 128 + b_col);
            float4 bv1 = *reinterpret_cast<const float4*>(W1 + (size_t)(k0 + b_row + 8) * W1ld + half * 128 + b_col);

            HsFlat[(a_col + 0) * 128 + a_row] = av0.x;
            HsFlat[(a_col + 1) * 128 + a_row] = av0.y;
            HsFlat[(a_col + 2) * 128 + a_row] = av0.z;
            HsFlat[(a_col + 3) * 128 + a_row] = av0.w;
            HsFlat[(a_col + 0) * 128 + a_row + 64] = av1.x;
            HsFlat[(a_col + 1) * 128 + a_row + 64] = av1.y;
            HsFlat[(a_col + 2) * 128 + a_row + 64] = av1.z;
            HsFlat[(a_col + 3) * 128 + a_row + 64] = av1.w;
            *reinterpret_cast<float4*>(&Bs[b_row][b_col]) = bv0;
            *reinterpret_cast<float4*>(&Bs[b_row + 8][b_col]) = bv1;
            __syncthreads();

#pragma unroll
            for (int k = 0; k < 16; ++k) {
                float4 a0 = *reinterpret_cast<const float4*>(&HsFlat[k * 128 + row0]);
                float4 a1 = *reinterpret_cast<const float4*>(&HsFlat[k * 128 + row0 + 64]);
                float4 b0 = *reinterpret_cast<const float4*>(&Bs[k][col0]);
                float4 b1 = *reinterpret_cast<const float4*>(&Bs[k][col0 + 64]);
                float ar[8] = {a0.x, a0.y, a0.z, a0.w, a1.x, a1.y, a1.z, a1.w};
                float br[8] = {b0.x, b0.y, b0.z, b0.w, b1.x, b1.y, b1.z, b1.w};
#pragma unroll
                for (int i = 0; i < 8; ++i)
#pragma unroll
                    for (int j = 0; j < 8; ++j)
                        accH[i][j] = fmaf(ar[i], br[j], accH[i][j]);
            }
            __syncthreads();
        }

        // ------------- h = ACT1(accH + b1half), store transposed -------------
#pragma unroll
        for (int i = 0; i < 8; ++i) {
            int r = row0 + (i < 4 ? i : 60 + i);
#pragma unroll
            for (int j = 0; j < 8; ++j) {
                int c = col0 + (j < 4 ? j : 60 + j);
                float v = accH[i][j] + b1v[half * 128 + c];
                if (ACT1 == 1) v = fmaxf(v, 0.0f);
                else           v = v > 0.0f ? v : (expf(v) - 1.0f);
                Hs[c][r] = v;
            }
        }
        __syncthreads();

        // ---------------- phase 2: accQ += h @ W2half ----------------
        for (int k0 = 0; k0 < 128; k0 += 16) {
            float4 bv0 = *reinterpret_cast<const float4*>(W2 + (size_t)(half * 128 + k0 + b_row) * 128 + b_col);
            float4 bv1 = *reinterpret_cast<const float4*>(W2 + (size_t)(half * 128 + k0 + b_row + 8) * 128 + b_col);
            *reinterpret_cast<float4*>(&Bs[b_row][b_col]) = bv0;
            *reinterpret_cast<float4*>(&Bs[b_row + 8][b_col]) = bv1;
            __syncthreads();

#pragma unroll
            for (int k = 0; k < 16; ++k) {
                float4 a0 = *reinterpret_cast<const float4*>(&Hs[k0 + k][row0]);
                float4 a1 = *reinterpret_cast<const float4*>(&Hs[k0 + k][row0 + 64]);
                float4 b0 = *reinterpret_cast<const float4*>(&Bs[k][col0]);
                float4 b1 = *reinterpret_cast<const float4*>(&Bs[k][col0 + 64]);
                float ar[8] = {a0.x, a0.y, a0.z, a0.w, a1.x, a1.y, a1.z, a1.w};
                float br[8] = {b0.x, b0.y, b0.z, b0.w, b1.x, b1.y, b1.z, b1.w};
#pragma unroll
                for (int i = 0; i < 8; ++i)
#pragma unroll
                    for (int j = 0; j < 8; ++j)
                        accQ[i][j] = fmaf(ar[i], br[j], accQ[i][j]);
            }
            __syncthreads();
        }
    }

    // ---------------- final epilogue ----------------
#pragma unroll
    for (int i = 0; i < 8; ++i) {
        int r = m_base + row0 + (i < 4 ? i : 60 + i);
        if (r >= M) continue;
#pragma unroll
        for (int jh = 0; jh < 2; ++jh) {
            int c = col0 + jh * 64;
            float4 v;
            v.x = accQ[i][jh * 4 + 0];
            v.y = accQ[i][jh * 4 + 1];
            v.z = accQ[i][jh * 4 + 2];
            v.w = accQ[i][jh * 4 + 3];
            if (FINAL_BIAS) {
                v.x += b2v[c + 0];
                v.y += b2v[c + 1];
                v.z += b2v[c + 2];
                v.w += b2v[c + 3];
            }
            *reinterpret_cast<float4*>(C + (size_t)r * 128 + c) = v;
        }
    }
}

// ---------------------------------------------------------------------------
// launch
// ---------------------------------------------------------------------------

extern "C" void kernel_launch(void* const* d_in, const int* in_sizes, int n_in,
                              void* d_out, int out_size, void* d_ws, size_t ws_size,
                              hipStream_t stream) {
    const float* x    = (const float*)d_in[0];
    const int*   ei   = (const int*)d_in[1];   // int64 in reference -> int32 from harness
    const float* W1   = (const float*)d_in[2]; // [128,256]
    const float* b1   = (const float*)d_in[3]; // [256]
    const float* W2   = (const float*)d_in[4]; // [256,128]
    const float* b2   = (const float*)d_in[5]; // [128]
    const float* fcW1 = (const float*)d_in[6]; // [128,128]
    const float* fcb1 = (const float*)d_in[7];
    const float* fcW2 = (const float*)d_in[8]; // [128,128]
    const float* fcb2 = (const float*)d_in[9];
    float* out        = (float*)d_out;         // [N,128], also ping-pong scratch

    char* ws = (char*)d_ws;
    size_t off = 0;
    auto alloc = [&](size_t bytes) {
        void* p = ws + off;
        off += (bytes + 255) & ~(size_t)255;
        return p;
    };
    int*   counts  = (int*)alloc(N_NODES * sizeof(int));
    int*   cursor  = (int*)alloc(N_NODES * sizeof(int));
    int*   part    = (int*)alloc(N_NODES * sizeof(int));
    int*   bsum    = (int*)alloc(SCAN_BLOCKS * sizeof(int));
    int*   boff    = (int*)alloc(SCAN_BLOCKS * sizeof(int));
    int*   offsets = (int*)alloc((N_NODES + 1) * sizeof(int));
    int*   csr     = (int*)alloc(N_EDGES * sizeof(int));
    float* dinv    = (float*)alloc(N_NODES * sizeof(float));
    float* Q       = (float*)alloc((size_t)N_NODES * 128 * sizeof(float));
    (void)ws_size; (void)n_in; (void)in_sizes; (void)out_size;

    // graph preprocessing
    k_zero<<<(N_NODES + 255) / 256, 256, 0, stream>>>(counts, cursor, N_NODES);
    k_count<<<(N_EDGES + 255) / 256, 256, 0, stream>>>(ei, counts);
    k_dinv<<<(N_NODES + 255) / 256, 256, 0, stream>>>(counts, dinv);
    k_scan1<<<SCAN_BLOCKS, 256, 0, stream>>>(counts, part, bsum);
    k_scan2<<<1, 256, 0, stream>>>(bsum, boff);
    k_scan3<<<SCAN_BLOCKS, 256, 0, stream>>>(part, counts, boff, offsets);
    k_fill<<<(N_EDGES + 255) / 256, 256, 0, stream>>>(ei, offsets, cursor, csr);

    const int prop_grid = (N_NODES + 3) / 4;
    const int gm = (N_NODES + 127) / 128;  // 391

    // layer 1 propagate (pre-GEMM side): agg = prop(x) -> out (scratch)
    k_prop<false, false><<<prop_grid, 256, 0, stream>>>(x, out, dinv, offsets, csr, nullptr);

    // fused mid: Q = relu(agg@W1 + b1) @ W2   (two K-halves in registers)
    k_fused<2, 1, false><<<gm, 256, 0, stream>>>(out, W1, b1, W2, nullptr, Q, N_NODES);

    // layer 2 propagate: z = relu(prop(Q) + b2) -> out
    k_prop<true, true><<<prop_grid, 256, 0, stream>>>(Q, out, dinv, offsets, csr, b2);

    // fused head (in-place): out = elu(out@fcW1 + fcb1) @ fcW2 + fcb2
    k_fused<1, 2, true><<<gm, 256, 0, stream>>>(out, fcW1, fcb1, fcW2, fcb2, out, N_NODES);
}

// Round 5
// 336.035 us; speedup vs baseline: 1.3833x; 1.1443x over previous
//
#include <hip/hip_runtime.h>
#include <hip/hip_bf16.h>
#include <cstdint>

#define N_NODES 50000
#define N_EDGES 800000
#define C128 128
#define SCAN_BLOCKS ((N_NODES + 255) / 256)   // 196

typedef __attribute__((ext_vector_type(8))) short bf16x8;
typedef __attribute__((ext_vector_type(4))) float f32x4;

__device__ __forceinline__ bf16x8 pack_bf16x8(unsigned int a, unsigned int b,
                                              unsigned int c, unsigned int d) {
    union { unsigned int u[4]; bf16x8 v; } x;
    x.u[0] = a; x.u[1] = b; x.u[2] = c; x.u[3] = d;
    return x.v;
}

__device__ __forceinline__ bf16x8 ld_frag(const unsigned int* p) {
    uint4 v = *reinterpret_cast<const uint4*>(p);
    return pack_bf16x8(v.x, v.y, v.z, v.w);
}

// ---------------------------------------------------------------------------
// init / graph preprocessing
// ---------------------------------------------------------------------------

__global__ void k_zero(int* __restrict__ a, int* __restrict__ b, int n) {
    int i = blockIdx.x * blockDim.x + threadIdx.x;
    if (i < n) { a[i] = 0; b[i] = 0; }
}

__device__ __forceinline__ int clamp_node(int v) {
    return v < 0 ? 0 : (v >= N_NODES ? N_NODES - 1 : v);
}

__global__ void k_count(const int* __restrict__ ei, int* __restrict__ counts) {
    int e = blockIdx.x * blockDim.x + threadIdx.x;
    if (e < N_EDGES) {
        int dst = clamp_node(ei[N_EDGES + e]);
        atomicAdd(&counts[dst], 1);
    }
}

__global__ void k_dinv(const int* __restrict__ counts, float* __restrict__ dinv) {
    int i = blockIdx.x * blockDim.x + threadIdx.x;
    if (i < N_NODES) {
        dinv[i] = rsqrtf((float)counts[i] + 1.0f);
    }
}

__global__ __launch_bounds__(256) void k_scan1(const int* __restrict__ counts,
                                               int* __restrict__ part,
                                               int* __restrict__ bsum) {
    __shared__ int s[256];
    const int tid = threadIdx.x;
    const int i = blockIdx.x * 256 + tid;
    int v = (i < N_NODES) ? counts[i] : 0;
    s[tid] = v;
    __syncthreads();
    for (int off = 1; off < 256; off <<= 1) {
        int t = (tid >= off) ? s[tid - off] : 0;
        __syncthreads();
        s[tid] += t;
        __syncthreads();
    }
    if (i < N_NODES) part[i] = s[tid];
    if (tid == 255) bsum[blockIdx.x] = s[255];
}

__global__ __launch_bounds__(256) void k_scan2(const int* __restrict__ bsum,
                                               int* __restrict__ boff) {
    __shared__ int s[256];
    const int tid = threadIdx.x;
    int v = (tid < SCAN_BLOCKS) ? bsum[tid] : 0;
    s[tid] = v;
    __syncthreads();
    for (int off = 1; off < 256; off <<= 1) {
        int t = (tid >= off) ? s[tid - off] : 0;
        __syncthreads();
        s[tid] += t;
        __syncthreads();
    }
    if (tid < SCAN_BLOCKS) boff[tid] = s[tid] - v;
}

__global__ __launch_bounds__(256) void k_scan3(const int* __restrict__ part,
                                               const int* __restrict__ counts,
                                               const int* __restrict__ boff,
                                               int* __restrict__ offsets) {
    const int i = blockIdx.x * 256 + threadIdx.x;
    if (i < N_NODES) offsets[i] = part[i] - counts[i] + boff[blockIdx.x];
    if (i == 0) offsets[N_NODES] = N_EDGES;
}

__global__ void k_fill(const int* __restrict__ ei, const int* __restrict__ offsets,
                       int* __restrict__ cursor, int* __restrict__ csr) {
    int e = blockIdx.x * blockDim.x + threadIdx.x;
    if (e < N_EDGES) {
        int src = clamp_node(ei[e]);
        int dst = clamp_node(ei[N_EDGES + e]);
        int pos = atomicAdd(&cursor[dst], 1);
        int slot = offsets[dst] + pos;
        if (slot < N_EDGES) csr[slot] = src;
    }
}

// ---------------------------------------------------------------------------
// Weight prep: split each weight into bf16 hi/lo and lay out as MFMA B-frags.
// Section s, frag f=(nf*4+kf): lane l holds B[k=kf*32+(l>>4)*8+j][n=nf*16+(l&15)]
// for j=0..7, packed as bf16x8 (4 u32 hi, then 4 u32 lo). Entry = 8 u32/lane.
// Sections: 0,1 = W1 halves (N-split); 2,3 = W2 halves (K-split); 4 = fcW1; 5 = fcW2.
// ---------------------------------------------------------------------------

__global__ __launch_bounds__(64) void k_prep(const float* __restrict__ W1,
                                             const float* __restrict__ W2,
                                             const float* __restrict__ fcW1,
                                             const float* __restrict__ fcW2,
                                             unsigned int* __restrict__ ftab) {
    int bx = blockIdx.x;          // 0..191
    int s = bx >> 5, f = bx & 31;
    int nf = f >> 2, kf = f & 3;
    int l = threadIdx.x;
    const float* src; int ld, roff, coff;
    switch (s) {
        case 0:  src = W1;   ld = 256; roff = 0;   coff = 0;   break;
        case 1:  src = W1;   ld = 256; roff = 0;   coff = 128; break;
        case 2:  src = W2;   ld = 128; roff = 0;   coff = 0;   break;
        case 3:  src = W2;   ld = 128; roff = 128; coff = 0;   break;
        case 4:  src = fcW1; ld = 128; roff = 0;   coff = 0;   break;
        default: src = fcW2; ld = 128; roff = 0;   coff = 0;   break;
    }
    int col = coff + nf * 16 + (l & 15);
    int krow = roff + kf * 32 + (l >> 4) * 8;
    unsigned int hp[4], lp[4];
#pragma unroll
    for (int p = 0; p < 4; ++p) {
        float a0 = src[(size_t)(krow + 2 * p) * ld + col];
        float a1 = src[(size_t)(krow + 2 * p + 1) * ld + col];
        unsigned int h0 = __float_as_uint(a0) & 0xFFFF0000u;
        unsigned int h1 = __float_as_uint(a1) & 0xFFFF0000u;
        float r0 = a0 - __uint_as_float(h0);
        float r1 = a1 - __uint_as_float(h1);
        hp[p] = (h0 >> 16) | h1;
        lp[p] = ((__float_as_uint(r0) & 0xFFFF0000u) >> 16) |
                (__float_as_uint(r1) & 0xFFFF0000u);
    }
    unsigned int* dst = ftab + ((size_t)bx * 64 + l) * 8;
    *reinterpret_cast<uint4*>(dst)     = make_uint4(hp[0], hp[1], hp[2], hp[3]);
    *reinterpret_cast<uint4*>(dst + 4) = make_uint4(lp[0], lp[1], lp[2], lp[3]);
}

// ---------------------------------------------------------------------------
// Propagation (unchanged)
// ---------------------------------------------------------------------------

template <bool HAS_BIAS, bool RELU>
__global__ __launch_bounds__(256) void k_prop(const float* __restrict__ in,
                                              float* __restrict__ out,
                                              const float* __restrict__ dinv,
                                              const int* __restrict__ offsets,
                                              const int* __restrict__ csr,
                                              const float* __restrict__ bias) {
    const int wave = threadIdx.x >> 6;
    const int lane = threadIdx.x & 63;
    const int node = blockIdx.x * 4 + wave;
    if (node >= N_NODES) return;

    const float di = dinv[node];
    float2 sv = reinterpret_cast<const float2*>(in + (size_t)node * C128)[lane];
    float acc0 = di * sv.x;
    float acc1 = di * sv.y;

    int e = offsets[node];
    const int eend = offsets[node + 1];
    for (; e + 4 <= eend; e += 4) {
        int s0 = csr[e + 0], s1 = csr[e + 1], s2 = csr[e + 2], s3 = csr[e + 3];
        float w0 = dinv[s0], w1 = dinv[s1], w2 = dinv[s2], w3 = dinv[s3];
        float2 v0 = reinterpret_cast<const float2*>(in + (size_t)s0 * C128)[lane];
        float2 v1 = reinterpret_cast<const float2*>(in + (size_t)s1 * C128)[lane];
        float2 v2 = reinterpret_cast<const float2*>(in + (size_t)s2 * C128)[lane];
        float2 v3 = reinterpret_cast<const float2*>(in + (size_t)s3 * C128)[lane];
        acc0 = fmaf(w0, v0.x, acc0); acc1 = fmaf(w0, v0.y, acc1);
        acc0 = fmaf(w1, v1.x, acc0); acc1 = fmaf(w1, v1.y, acc1);
        acc0 = fmaf(w2, v2.x, acc0); acc1 = fmaf(w2, v2.y, acc1);
        acc0 = fmaf(w3, v3.x, acc0); acc1 = fmaf(w3, v3.y, acc1);
    }
    for (; e < eend; ++e) {
        int s = csr[e];
        float w = dinv[s];
        float2 v = reinterpret_cast<const float2*>(in + (size_t)s * C128)[lane];
        acc0 = fmaf(w, v.x, acc0);
        acc1 = fmaf(w, v.y, acc1);
    }

    float o0 = di * acc0;
    float o1 = di * acc1;
    if (HAS_BIAS) {
        o0 += bias[2 * lane + 0];
        o1 += bias[2 * lane + 1];
    }
    if (RELU) {
        o0 = fmaxf(o0, 0.0f);
        o1 = fmaxf(o1, 0.0f);
    }
    reinterpret_cast<float2*>(out + (size_t)node * C128)[lane] = make_float2(o0, o1);
}

// ---------------------------------------------------------------------------
// Fused 2-GEMM chain on MFMA (split-bf16, 3 products: hi*hi + hi*lo + lo*hi).
//   per half: H = ACT1(A @ W1[half] + b1[half]);  accQ += H @ W2[half]
//   C = accQ (+ b2 if FINAL_BIAS)
// 4 waves/block; wave owns 32 output rows. H kept per-wave in swizzled LDS
// as u32 = (hi_bf16 | lo_bf16<<16). In-place C==A safe (own rows only).
// ---------------------------------------------------------------------------

template <int NHALF, int ACT1, bool FINAL_BIAS>
__global__ __launch_bounds__(256, 2) void k_fused(
        const float* __restrict__ A,
        const unsigned int* __restrict__ ftabW1,
        const unsigned int* __restrict__ ftabW2,
        const float* __restrict__ b1v,
        const float* __restrict__ b2v,
        float* __restrict__ C, int M) {
    __shared__ unsigned int Hs[4 * 32 * 128];   // 64 KB
    const int tid = threadIdx.x;
    const int wave = tid >> 6, l = tid & 63;
    const int l15 = l & 15, l4 = l >> 4;
    const int m_base = blockIdx.x * 128 + wave * 32;
    unsigned int* Hw = Hs + wave * (32 * 128);

    f32x4 accQ[2][8] = {};

    for (int half = 0; half < NHALF; ++half) {
        // ---------------- phase 1: accH = A @ W1[half] ----------------
        f32x4 accH[2][8] = {};
        for (int kf = 0; kf < 4; ++kf) {
            bf16x8 ahi[2], alo[2];
#pragma unroll
            for (int mf = 0; mf < 2; ++mf) {
                int r = m_base + mf * 16 + l15;
                if (r >= M) r = M - 1;
                const float* ap = A + (size_t)r * 128 + kf * 32 + l4 * 8;
                float4 v0 = *reinterpret_cast<const float4*>(ap);
                float4 v1 = *reinterpret_cast<const float4*>(ap + 4);
                float av[8] = {v0.x, v0.y, v0.z, v0.w, v1.x, v1.y, v1.z, v1.w};
                unsigned int hp[4], lp[4];
#pragma unroll
                for (int p = 0; p < 4; ++p) {
                    float a0 = av[2 * p], a1 = av[2 * p + 1];
                    unsigned int h0 = __float_as_uint(a0) & 0xFFFF0000u;
                    unsigned int h1 = __float_as_uint(a1) & 0xFFFF0000u;
                    float r0 = a0 - __uint_as_float(h0);
                    float r1 = a1 - __uint_as_float(h1);
                    hp[p] = (h0 >> 16) | h1;
                    lp[p] = ((__float_as_uint(r0) & 0xFFFF0000u) >> 16) |
                            (__float_as_uint(r1) & 0xFFFF0000u);
                }
                ahi[mf] = pack_bf16x8(hp[0], hp[1], hp[2], hp[3]);
                alo[mf] = pack_bf16x8(lp[0], lp[1], lp[2], lp[3]);
            }
#pragma unroll
            for (int nf = 0; nf < 8; ++nf) {
                const unsigned int* fp =
                    ftabW1 + (((size_t)half * 32 + nf * 4 + kf) * 64 + l) * 8;
                bf16x8 bhi = ld_frag(fp);
                bf16x8 blo = ld_frag(fp + 4);
#pragma unroll
                for (int mf = 0; mf < 2; ++mf) {
                    accH[mf][nf] = __builtin_amdgcn_mfma_f32_16x16x32_bf16(ahi[mf], bhi, accH[mf][nf], 0, 0, 0);
                    accH[mf][nf] = __builtin_amdgcn_mfma_f32_16x16x32_bf16(ahi[mf], blo, accH[mf][nf], 0, 0, 0);
                    accH[mf][nf] = __builtin_amdgcn_mfma_f32_16x16x32_bf16(alo[mf], bhi, accH[mf][nf], 0, 0, 0);
                }
            }
        }

        // -------- epilogue 1: H = ACT1(accH + b1), split+pack to LDS --------
#pragma unroll
        for (int mf = 0; mf < 2; ++mf) {
#pragma unroll
            for (int nf = 0; nf < 8; ++nf) {
                float bias = b1v[half * 128 + nf * 16 + l15];
#pragma unroll
                for (int reg = 0; reg < 4; ++reg) {
                    float v = accH[mf][nf][reg] + bias;
                    if (ACT1 == 1) v = fmaxf(v, 0.0f);
                    else           v = v > 0.0f ? v : (expf(v) - 1.0f);
                    unsigned int vh = __float_as_uint(v) & 0xFFFF0000u;
                    float rr = v - __uint_as_float(vh);
                    unsigned int pack = (vh >> 16) |
                                        (__float_as_uint(rr) & 0xFFFF0000u);
                    int row = mf * 16 + l4 * 4 + reg;
                    int col = nf * 16 + l15;
                    int cofs = (((col >> 3) ^ (row & 15)) << 3) | (col & 7);
                    Hw[row * 128 + cofs] = pack;
                }
            }
        }
        __syncthreads();

        // ---------------- phase 2: accQ += H @ W2[half] ----------------
        for (int kf = 0; kf < 4; ++kf) {
            bf16x8 ahi[2], alo[2];
#pragma unroll
            for (int mf = 0; mf < 2; ++mf) {
                int row = mf * 16 + l15;
                int cs = (((kf * 4 + l4) ^ l15) << 3);
                const unsigned int* hp = Hw + row * 128 + cs;
                uint4 w0 = *reinterpret_cast<const uint4*>(hp);
                uint4 w1 = *reinterpret_cast<const uint4*>(hp + 4);
                unsigned int h0 = (w0.x & 0xFFFFu) | (w0.y << 16);
                unsigned int h1 = (w0.z & 0xFFFFu) | (w0.w << 16);
                unsigned int h2 = (w1.x & 0xFFFFu) | (w1.y << 16);
                unsigned int h3 = (w1.z & 0xFFFFu) | (w1.w << 16);
                unsigned int g0 = (w0.x >> 16) | (w0.y & 0xFFFF0000u);
                unsigned int g1 = (w0.z >> 16) | (w0.w & 0xFFFF0000u);
                unsigned int g2 = (w1.x >> 16) | (w1.y & 0xFFFF0000u);
                unsigned int g3 = (w1.z >> 16) | (w1.w & 0xFFFF0000u);
                ahi[mf] = pack_bf16x8(h0, h1, h2, h3);
                alo[mf] = pack_bf16x8(g0, g1, g2, g3);
            }
#pragma unroll
            for (int nf = 0; nf < 8; ++nf) {
                const unsigned int* fp =
                    ftabW2 + (((size_t)half * 32 + nf * 4 + kf) * 64 + l) * 8;
                bf16x8 bhi = ld_frag(fp);
                bf16x8 blo = ld_frag(fp + 4);
#pragma unroll
                for (int mf = 0; mf < 2; ++mf) {
                    accQ[mf][nf] = __builtin_amdgcn_mfma_f32_16x16x32_bf16(ahi[mf], bhi, accQ[mf][nf], 0, 0, 0);
                    accQ[mf][nf] = __builtin_amdgcn_mfma_f32_16x16x32_bf16(ahi[mf], blo, accQ[mf][nf], 0, 0, 0);
                    accQ[mf][nf] = __builtin_amdgcn_mfma_f32_16x16x32_bf16(alo[mf], bhi, accQ[mf][nf], 0, 0, 0);
                }
            }
        }
        __syncthreads();
    }

    // ---------------- final epilogue ----------------
#pragma unroll
    for (int mf = 0; mf < 2; ++mf) {
#pragma unroll
        for (int nf = 0; nf < 8; ++nf) {
            float bias = FINAL_BIAS ? b2v[nf * 16 + l15] : 0.0f;
#pragma unroll
            for (int reg = 0; reg < 4; ++reg) {
                int r = m_base + mf * 16 + l4 * 4 + reg;
                if (r < M) C[(size_t)r * 128 + nf * 16 + l15] = accQ[mf][nf][reg] + bias;
            }
        }
    }
}

// ---------------------------------------------------------------------------
// launch
// ---------------------------------------------------------------------------

extern "C" void kernel_launch(void* const* d_in, const int* in_sizes, int n_in,
                              void* d_out, int out_size, void* d_ws, size_t ws_size,
                              hipStream_t stream) {
    const float* x    = (const float*)d_in[0];
    const int*   ei   = (const int*)d_in[1];   // int64 in reference -> int32 from harness
    const float* W1   = (const float*)d_in[2]; // [128,256]
    const float* b1   = (const float*)d_in[3];
    const float* W2   = (const float*)d_in[4]; // [256,128]
    const float* b2   = (const float*)d_in[5];
    const float* fcW1 = (const float*)d_in[6]; // [128,128]
    const float* fcb1 = (const float*)d_in[7];
    const float* fcW2 = (const float*)d_in[8]; // [128,128]
    const float* fcb2 = (const float*)d_in[9];
    float* out        = (float*)d_out;         // [N,128], also ping-pong scratch

    char* ws = (char*)d_ws;
    size_t off = 0;
    auto alloc = [&](size_t bytes) {
        void* p = ws + off;
        off += (bytes + 255) & ~(size_t)255;
        return p;
    };
    int*   counts  = (int*)alloc(N_NODES * sizeof(int));
    int*   cursor  = (int*)alloc(N_NODES * sizeof(int));
    int*   part    = (int*)alloc(N_NODES * sizeof(int));
    int*   bsum    = (int*)alloc(SCAN_BLOCKS * sizeof(int));
    int*   boff    = (int*)alloc(SCAN_BLOCKS * sizeof(int));
    int*   offsets = (int*)alloc((N_NODES + 1) * sizeof(int));
    int*   csr     = (int*)alloc(N_EDGES * sizeof(int));
    float* dinv    = (float*)alloc(N_NODES * sizeof(float));
    unsigned int* ftab = (unsigned int*)alloc((size_t)192 * 64 * 8 * sizeof(unsigned int));
    float* Q       = (float*)alloc((size_t)N_NODES * 128 * sizeof(float));
    (void)ws_size; (void)n_in; (void)in_sizes; (void)out_size;

    const unsigned int SEC = 32 * 64 * 8;  // u32 per section

    // graph preprocessing + weight prep
    k_zero<<<(N_NODES + 255) / 256, 256, 0, stream>>>(counts, cursor, N_NODES);
    k_prep<<<192, 64, 0, stream>>>(W1, W2, fcW1, fcW2, ftab);
    k_count<<<(N_EDGES + 255) / 256, 256, 0, stream>>>(ei, counts);
    k_dinv<<<(N_NODES + 255) / 256, 256, 0, stream>>>(counts, dinv);
    k_scan1<<<SCAN_BLOCKS, 256, 0, stream>>>(counts, part, bsum);
    k_scan2<<<1, 256, 0, stream>>>(bsum, boff);
    k_scan3<<<SCAN_BLOCKS, 256, 0, stream>>>(part, counts, boff, offsets);
    k_fill<<<(N_EDGES + 255) / 256, 256, 0, stream>>>(ei, offsets, cursor, csr);

    const int prop_grid = (N_NODES + 3) / 4;
    const int gm = (N_NODES + 127) / 128;  // 391

    // layer 1 propagate (pre-GEMM side): agg = prop(x) -> out (scratch)
    k_prop<false, false><<<prop_grid, 256, 0, stream>>>(x, out, dinv, offsets, csr, nullptr);

    // fused mid: Q = relu(agg@W1 + b1) @ W2
    k_fused<2, 1, false><<<gm, 256, 0, stream>>>(out, ftab, ftab + 2 * SEC,
                                                 b1, nullptr, Q, N_NODES);

    // layer 2 propagate: z = relu(prop(Q) + b2) -> out
    k_prop<true, true><<<prop_grid, 256, 0, stream>>>(Q, out, dinv, offsets, csr, b2);

    // fused head (in-place): out = elu(out@fcW1 + fcb1) @ fcW2 + fcb2
    k_fused<1, 2, true><<<gm, 256, 0, stream>>>(out, ftab + 4 * SEC, ftab + 5 * SEC,
                                                fcb1, fcb2, out, N_NODES);
}

// Round 6
// 325.938 us; speedup vs baseline: 1.4261x; 1.0310x over previous
//
#include <hip/hip_runtime.h>
#include <hip/hip_bf16.h>
#include <cstdint>

#define N_NODES 50000
#define N_EDGES 800000
#define C128 128
#define SCAN_BLOCKS ((N_NODES + 255) / 256)   // 196

typedef __attribute__((ext_vector_type(8))) short bf16x8;
typedef __attribute__((ext_vector_type(4))) float f32x4;

__device__ __forceinline__ bf16x8 pack_bf16x8(unsigned int a, unsigned int b,
                                              unsigned int c, unsigned int d) {
    union { unsigned int u[4]; bf16x8 v; } x;
    x.u[0] = a; x.u[1] = b; x.u[2] = c; x.u[3] = d;
    return x.v;
}

__device__ __forceinline__ bf16x8 ld_frag(const unsigned int* p) {
    uint4 v = *reinterpret_cast<const uint4*>(p);
    return pack_bf16x8(v.x, v.y, v.z, v.w);
}

// ---------------------------------------------------------------------------
// init / graph preprocessing
// ---------------------------------------------------------------------------

__global__ void k_zero(int* __restrict__ a, int* __restrict__ b, int n) {
    int i = blockIdx.x * blockDim.x + threadIdx.x;
    if (i < n) { a[i] = 0; b[i] = 0; }
}

__device__ __forceinline__ int clamp_node(int v) {
    return v < 0 ? 0 : (v >= N_NODES ? N_NODES - 1 : v);
}

__global__ void k_count(const int* __restrict__ ei, int* __restrict__ counts) {
    int e = blockIdx.x * blockDim.x + threadIdx.x;
    if (e < N_EDGES) {
        int dst = clamp_node(ei[N_EDGES + e]);
        atomicAdd(&counts[dst], 1);
    }
}

__global__ void k_dinv(const int* __restrict__ counts, float* __restrict__ dinv) {
    int i = blockIdx.x * blockDim.x + threadIdx.x;
    if (i < N_NODES) {
        dinv[i] = rsqrtf((float)counts[i] + 1.0f);
    }
}

__global__ __launch_bounds__(256) void k_scan1(const int* __restrict__ counts,
                                               int* __restrict__ part,
                                               int* __restrict__ bsum) {
    __shared__ int s[256];
    const int tid = threadIdx.x;
    const int i = blockIdx.x * 256 + tid;
    int v = (i < N_NODES) ? counts[i] : 0;
    s[tid] = v;
    __syncthreads();
    for (int off = 1; off < 256; off <<= 1) {
        int t = (tid >= off) ? s[tid - off] : 0;
        __syncthreads();
        s[tid] += t;
        __syncthreads();
    }
    if (i < N_NODES) part[i] = s[tid];
    if (tid == 255) bsum[blockIdx.x] = s[255];
}

__global__ __launch_bounds__(256) void k_scan2(const int* __restrict__ bsum,
                                               int* __restrict__ boff) {
    __shared__ int s[256];
    const int tid = threadIdx.x;
    int v = (tid < SCAN_BLOCKS) ? bsum[tid] : 0;
    s[tid] = v;
    __syncthreads();
    for (int off = 1; off < 256; off <<= 1) {
        int t = (tid >= off) ? s[tid - off] : 0;
        __syncthreads();
        s[tid] += t;
        __syncthreads();
    }
    if (tid < SCAN_BLOCKS) boff[tid] = s[tid] - v;
}

__global__ __launch_bounds__(256) void k_scan3(const int* __restrict__ part,
                                               const int* __restrict__ counts,
                                               const int* __restrict__ boff,
                                               int* __restrict__ offsets) {
    const int i = blockIdx.x * 256 + threadIdx.x;
    if (i < N_NODES) offsets[i] = part[i] - counts[i] + boff[blockIdx.x];
    if (i == 0) offsets[N_NODES] = N_EDGES;
}

__global__ void k_fill(const int* __restrict__ ei, const int* __restrict__ offsets,
                       int* __restrict__ cursor, int* __restrict__ csr) {
    int e = blockIdx.x * blockDim.x + threadIdx.x;
    if (e < N_EDGES) {
        int src = clamp_node(ei[e]);
        int dst = clamp_node(ei[N_EDGES + e]);
        int pos = atomicAdd(&cursor[dst], 1);
        int slot = offsets[dst] + pos;
        if (slot < N_EDGES) csr[slot] = src;
    }
}

// ---------------------------------------------------------------------------
// Weight prep: split each weight into bf16 hi/lo and lay out as MFMA fragments.
// Section s, frag f=(nf*4+kf): lane l holds W[k=kf*32+(l>>4)*8+j][n=nf*16+(l&15)]
// for j=0..7, packed as bf16x8 (4 u32 hi, then 4 u32 lo). Entry = 8 u32/lane.
// Used as arg0 (=W^T) of transposed-product MFMAs.
// Sections: 0,1 = W1 halves (N-split); 2,3 = W2 halves (K-split); 4 = fcW1; 5 = fcW2.
// ---------------------------------------------------------------------------

__global__ __launch_bounds__(64) void k_prep(const float* __restrict__ W1,
                                             const float* __restrict__ W2,
                                             const float* __restrict__ fcW1,
                                             const float* __restrict__ fcW2,
                                             unsigned int* __restrict__ ftab) {
    int bx = blockIdx.x;          // 0..191
    int s = bx >> 5, f = bx & 31;
    int nf = f >> 2, kf = f & 3;
    int l = threadIdx.x;
    const float* src; int ld, roff, coff;
    switch (s) {
        case 0:  src = W1;   ld = 256; roff = 0;   coff = 0;   break;
        case 1:  src = W1;   ld = 256; roff = 0;   coff = 128; break;
        case 2:  src = W2;   ld = 128; roff = 0;   coff = 0;   break;
        case 3:  src = W2;   ld = 128; roff = 128; coff = 0;   break;
        case 4:  src = fcW1; ld = 128; roff = 0;   coff = 0;   break;
        default: src = fcW2; ld = 128; roff = 0;   coff = 0;   break;
    }
    int col = coff + nf * 16 + (l & 15);
    int krow = roff + kf * 32 + (l >> 4) * 8;
    unsigned int hp[4], lp[4];
#pragma unroll
    for (int p = 0; p < 4; ++p) {
        float a0 = src[(size_t)(krow + 2 * p) * ld + col];
        float a1 = src[(size_t)(krow + 2 * p + 1) * ld + col];
        unsigned int h0 = __float_as_uint(a0) & 0xFFFF0000u;
        unsigned int h1 = __float_as_uint(a1) & 0xFFFF0000u;
        float r0 = a0 - __uint_as_float(h0);
        float r1 = a1 - __uint_as_float(h1);
        hp[p] = (h0 >> 16) | h1;
        lp[p] = ((__float_as_uint(r0) & 0xFFFF0000u) >> 16) |
                (__float_as_uint(r1) & 0xFFFF0000u);
    }
    unsigned int* dst = ftab + ((size_t)bx * 64 + l) * 8;
    *reinterpret_cast<uint4*>(dst)     = make_uint4(hp[0], hp[1], hp[2], hp[3]);
    *reinterpret_cast<uint4*>(dst + 4) = make_uint4(lp[0], lp[1], lp[2], lp[3]);
}

// ---------------------------------------------------------------------------
// Propagation (unchanged)
// ---------------------------------------------------------------------------

template <bool HAS_BIAS, bool RELU>
__global__ __launch_bounds__(256) void k_prop(const float* __restrict__ in,
                                              float* __restrict__ out,
                                              const float* __restrict__ dinv,
                                              const int* __restrict__ offsets,
                                              const int* __restrict__ csr,
                                              const float* __restrict__ bias) {
    const int wave = threadIdx.x >> 6;
    const int lane = threadIdx.x & 63;
    const int node = blockIdx.x * 4 + wave;
    if (node >= N_NODES) return;

    const float di = dinv[node];
    float2 sv = reinterpret_cast<const float2*>(in + (size_t)node * C128)[lane];
    float acc0 = di * sv.x;
    float acc1 = di * sv.y;

    int e = offsets[node];
    const int eend = offsets[node + 1];
    for (; e + 4 <= eend; e += 4) {
        int s0 = csr[e + 0], s1 = csr[e + 1], s2 = csr[e + 2], s3 = csr[e + 3];
        float w0 = dinv[s0], w1 = dinv[s1], w2 = dinv[s2], w3 = dinv[s3];
        float2 v0 = reinterpret_cast<const float2*>(in + (size_t)s0 * C128)[lane];
        float2 v1 = reinterpret_cast<const float2*>(in + (size_t)s1 * C128)[lane];
        float2 v2 = reinterpret_cast<const float2*>(in + (size_t)s2 * C128)[lane];
        float2 v3 = reinterpret_cast<const float2*>(in + (size_t)s3 * C128)[lane];
        acc0 = fmaf(w0, v0.x, acc0); acc1 = fmaf(w0, v0.y, acc1);
        acc0 = fmaf(w1, v1.x, acc0); acc1 = fmaf(w1, v1.y, acc1);
        acc0 = fmaf(w2, v2.x, acc0); acc1 = fmaf(w2, v2.y, acc1);
        acc0 = fmaf(w3, v3.x, acc0); acc1 = fmaf(w3, v3.y, acc1);
    }
    for (; e < eend; ++e) {
        int s = csr[e];
        float w = dinv[s];
        float2 v = reinterpret_cast<const float2*>(in + (size_t)s * C128)[lane];
        acc0 = fmaf(w, v.x, acc0);
        acc1 = fmaf(w, v.y, acc1);
    }

    float o0 = di * acc0;
    float o1 = di * acc1;
    if (HAS_BIAS) {
        o0 += bias[2 * lane + 0];
        o1 += bias[2 * lane + 1];
    }
    if (RELU) {
        o0 = fmaxf(o0, 0.0f);
        o1 = fmaxf(o1, 0.0f);
    }
    reinterpret_cast<float2*>(out + (size_t)node * C128)[lane] = make_float2(o0, o1);
}

// ---------------------------------------------------------------------------
// Fused 2-GEMM chain on MFMA, TRANSPOSED products, no LDS, no barriers.
//   per half: H^T = W1h^T · A^T (acc layout: row=n_hidden, col=m)
//             act+bias, split-pack hi/lo
//             Q^T += W2h^T · H^T  (H^T frags built via 16-lane shuffles)
//   C[m][n] = Q^T[n][m] (+ b2), float4 row stores.
// 4 independent waves/block; each wave owns 16 output rows.
// In-place C==A safe: each wave reads only its own 16 rows before writing them.
// ACT1: 1 = relu, 2 = elu
// ---------------------------------------------------------------------------

template <int NHALF, int ACT1, bool FINAL_BIAS>
__global__ __launch_bounds__(256) void k_fused(
        const float* __restrict__ A,
        const unsigned int* __restrict__ ftabW1,
        const unsigned int* __restrict__ ftabW2,
        const float* __restrict__ b1v,
        const float* __restrict__ b2v,
        float* __restrict__ C, int M) {
    const int tid = threadIdx.x;
    const int wave = tid >> 6, l = tid & 63;
    const int l15 = l & 15, l4 = l >> 4;
    const int m_base = blockIdx.x * 64 + wave * 16;
    const int r = m_base + l15;
    const int rc = r < M ? r : M - 1;
    const float* arow = A + (size_t)rc * 128;

    f32x4 accQ[8] = {};   // accQ[nf][reg] = Q[r][nf*16 + l4*4 + reg]

    for (int half = 0; half < NHALF; ++half) {
        // ---- load A fragments (arg1 of phase 1): 8 consecutive floats/lane ----
        bf16x8 ahi[4], alo[4];
#pragma unroll
        for (int kf = 0; kf < 4; ++kf) {
            const float* ap = arow + kf * 32 + l4 * 8;
            float4 v0 = *reinterpret_cast<const float4*>(ap);
            float4 v1 = *reinterpret_cast<const float4*>(ap + 4);
            float av[8] = {v0.x, v0.y, v0.z, v0.w, v1.x, v1.y, v1.z, v1.w};
            unsigned int hp[4], lp[4];
#pragma unroll
            for (int p = 0; p < 4; ++p) {
                float a0 = av[2 * p], a1 = av[2 * p + 1];
                unsigned int h0 = __float_as_uint(a0) & 0xFFFF0000u;
                unsigned int h1 = __float_as_uint(a1) & 0xFFFF0000u;
                float r0 = a0 - __uint_as_float(h0);
                float r1 = a1 - __uint_as_float(h1);
                hp[p] = (h0 >> 16) | h1;
                lp[p] = ((__float_as_uint(r0) & 0xFFFF0000u) >> 16) |
                        (__float_as_uint(r1) & 0xFFFF0000u);
            }
            ahi[kf] = pack_bf16x8(hp[0], hp[1], hp[2], hp[3]);
            alo[kf] = pack_bf16x8(lp[0], lp[1], lp[2], lp[3]);
        }

        // ---- phase 1: accH = H^T frags (row = n_hidden, col = m) ----
        f32x4 accH[8] = {};
#pragma unroll
        for (int kf = 0; kf < 4; ++kf) {
#pragma unroll
            for (int nf = 0; nf < 8; ++nf) {
                const unsigned int* fp =
                    ftabW1 + (((size_t)half * 32 + nf * 4 + kf) * 64 + l) * 8;
                bf16x8 whi = ld_frag(fp);
                bf16x8 wlo = ld_frag(fp + 4);
                accH[nf] = __builtin_amdgcn_mfma_f32_16x16x32_bf16(whi, ahi[kf], accH[nf], 0, 0, 0);
                accH[nf] = __builtin_amdgcn_mfma_f32_16x16x32_bf16(whi, alo[kf], accH[nf], 0, 0, 0);
                accH[nf] = __builtin_amdgcn_mfma_f32_16x16x32_bf16(wlo, ahi[kf], accH[nf], 0, 0, 0);
            }
        }

        // ---- epilogue 1: bias + act, split-pack (hi | lo<<16) ----
        unsigned int hpk[8][4];
#pragma unroll
        for (int nf = 0; nf < 8; ++nf) {
#pragma unroll
            for (int reg = 0; reg < 4; ++reg) {
                float v = accH[nf][reg] + b1v[half * 128 + nf * 16 + l4 * 4 + reg];
                if (ACT1 == 1) v = fmaxf(v, 0.0f);
                else           v = v > 0.0f ? v : (expf(v) - 1.0f);
                unsigned int vh = __float_as_uint(v) & 0xFFFF0000u;
                float rr = v - __uint_as_float(vh);
                hpk[nf][reg] = (vh >> 16) | (__float_as_uint(rr) & 0xFFFF0000u);
            }
        }

        // ---- phase 2: accQ += W2h^T · H^T ----
#pragma unroll
        for (int kf = 0; kf < 4; ++kf) {
            // build H^T fragment (arg1): lane needs H^T[kf*32 + l4*8 + je][m=l15]
            unsigned int got[8];
#pragma unroll
            for (int je = 0; je < 8; ++je) {
                int srcLane = ((l4 & 1) * 2 + (je >> 2)) * 16 + l15;
                unsigned int g0 = __shfl(hpk[2 * kf][je & 3], srcLane, 64);
                unsigned int g1 = __shfl(hpk[2 * kf + 1][je & 3], srcLane, 64);
                got[je] = (l4 & 2) ? g1 : g0;
            }
            unsigned int hh[4], gg[4];
#pragma unroll
            for (int p = 0; p < 4; ++p) {
                hh[p] = (got[2 * p] & 0xFFFFu) | (got[2 * p + 1] << 16);
                gg[p] = (got[2 * p] >> 16) | (got[2 * p + 1] & 0xFFFF0000u);
            }
            bf16x8 bh = pack_bf16x8(hh[0], hh[1], hh[2], hh[3]);
            bf16x8 bl = pack_bf16x8(gg[0], gg[1], gg[2], gg[3]);
#pragma unroll
            for (int nf = 0; nf < 8; ++nf) {
                const unsigned int* fp =
                    ftabW2 + (((size_t)half * 32 + nf * 4 + kf) * 64 + l) * 8;
                bf16x8 whi = ld_frag(fp);
                bf16x8 wlo = ld_frag(fp + 4);
                accQ[nf] = __builtin_amdgcn_mfma_f32_16x16x32_bf16(whi, bh, accQ[nf], 0, 0, 0);
                accQ[nf] = __builtin_amdgcn_mfma_f32_16x16x32_bf16(whi, bl, accQ[nf], 0, 0, 0);
                accQ[nf] = __builtin_amdgcn_mfma_f32_16x16x32_bf16(wlo, bh, accQ[nf], 0, 0, 0);
            }
        }
    }

    // ---- final epilogue: C[r][nf*16 + l4*4 .. +3] = accQ[nf] (+b2) ----
    if (r < M) {
#pragma unroll
        for (int nf = 0; nf < 8; ++nf) {
            float4 v;
            v.x = accQ[nf][0]; v.y = accQ[nf][1];
            v.z = accQ[nf][2]; v.w = accQ[nf][3];
            if (FINAL_BIAS) {
                const float* bb = b2v + nf * 16 + l4 * 4;
                v.x += bb[0]; v.y += bb[1]; v.z += bb[2]; v.w += bb[3];
            }
            *reinterpret_cast<float4*>(C + (size_t)r * 128 + nf * 16 + l4 * 4) = v;
        }
    }
}

// ---------------------------------------------------------------------------
// launch
// ---------------------------------------------------------------------------

extern "C" void kernel_launch(void* const* d_in, const int* in_sizes, int n_in,
                              void* d_out, int out_size, void* d_ws, size_t ws_size,
                              hipStream_t stream) {
    const float* x    = (const float*)d_in[0];
    const int*   ei   = (const int*)d_in[1];   // int64 in reference -> int32 from harness
    const float* W1   = (const float*)d_in[2]; // [128,256]
    const float* b1   = (const float*)d_in[3];
    const float* W2   = (const float*)d_in[4]; // [256,128]
    const float* b2   = (const float*)d_in[5];
    const float* fcW1 = (const float*)d_in[6]; // [128,128]
    const float* fcb1 = (const float*)d_in[7];
    const float* fcW2 = (const float*)d_in[8]; // [128,128]
    const float* fcb2 = (const float*)d_in[9];
    float* out        = (float*)d_out;         // [N,128], also ping-pong scratch

    char* ws = (char*)d_ws;
    size_t off = 0;
    auto alloc = [&](size_t bytes) {
        void* p = ws + off;
        off += (bytes + 255) & ~(size_t)255;
        return p;
    };
    int*   counts  = (int*)alloc(N_NODES * sizeof(int));
    int*   cursor  = (int*)alloc(N_NODES * sizeof(int));
    int*   part    = (int*)alloc(N_NODES * sizeof(int));
    int*   bsum    = (int*)alloc(SCAN_BLOCKS * sizeof(int));
    int*   boff    = (int*)alloc(SCAN_BLOCKS * sizeof(int));
    int*   offsets = (int*)alloc((N_NODES + 1) * sizeof(int));
    int*   csr     = (int*)alloc(N_EDGES * sizeof(int));
    float* dinv    = (float*)alloc(N_NODES * sizeof(float));
    unsigned int* ftab = (unsigned int*)alloc((size_t)192 * 64 * 8 * sizeof(unsigned int));
    float* Q       = (float*)alloc((size_t)N_NODES * 128 * sizeof(float));
    (void)ws_size; (void)n_in; (void)in_sizes; (void)out_size;

    const unsigned int SEC = 32 * 64 * 8;  // u32 per section

    // graph preprocessing + weight prep
    k_zero<<<(N_NODES + 255) / 256, 256, 0, stream>>>(counts, cursor, N_NODES);
    k_prep<<<192, 64, 0, stream>>>(W1, W2, fcW1, fcW2, ftab);
    k_count<<<(N_EDGES + 255) / 256, 256, 0, stream>>>(ei, counts);
    k_dinv<<<(N_NODES + 255) / 256, 256, 0, stream>>>(counts, dinv);
    k_scan1<<<SCAN_BLOCKS, 256, 0, stream>>>(counts, part, bsum);
    k_scan2<<<1, 256, 0, stream>>>(bsum, boff);
    k_scan3<<<SCAN_BLOCKS, 256, 0, stream>>>(part, counts, boff, offsets);
    k_fill<<<(N_EDGES + 255) / 256, 256, 0, stream>>>(ei, offsets, cursor, csr);

    const int prop_grid = (N_NODES + 3) / 4;
    const int gm = (N_NODES + 63) / 64;   // 782 (64 rows per block, 16 per wave)

    // layer 1 propagate (pre-GEMM side): agg = prop(x) -> out (scratch)
    k_prop<false, false><<<prop_grid, 256, 0, stream>>>(x, out, dinv, offsets, csr, nullptr);

    // fused mid: Q = relu(agg@W1 + b1) @ W2
    k_fused<2, 1, false><<<gm, 256, 0, stream>>>(out, ftab, ftab + 2 * SEC,
                                                 b1, nullptr, Q, N_NODES);

    // layer 2 propagate: z = relu(prop(Q) + b2) -> out
    k_prop<true, true><<<prop_grid, 256, 0, stream>>>(Q, out, dinv, offsets, csr, b2);

    // fused head (in-place): out = elu(out@fcW1 + fcb1) @ fcW2 + fcb2
    k_fused<1, 2, true><<<gm, 256, 0, stream>>>(out, ftab + 4 * SEC, ftab + 5 * SEC,
                                                fcb1, fcb2, out, N_NODES);
}

// Round 7
// 303.940 us; speedup vs baseline: 1.5293x; 1.0724x over previous
//
#include <hip/hip_runtime.h>
#include <hip/hip_bf16.h>
#include <cstdint>

#define N_NODES 50000
#define N_EDGES 800000
#define C128 128
#define SCAN_BLOCKS ((N_NODES + 255) / 256)   // 196

typedef __attribute__((ext_vector_type(8))) short bf16x8;
typedef __attribute__((ext_vector_type(4))) float f32x4;

__device__ __forceinline__ bf16x8 pack_bf16x8(unsigned int a, unsigned int b,
                                              unsigned int c, unsigned int d) {
    union { unsigned int u[4]; bf16x8 v; } x;
    x.u[0] = a; x.u[1] = b; x.u[2] = c; x.u[3] = d;
    return x.v;
}

__device__ __forceinline__ bf16x8 as_bf16x8(uint4 v) {
    union { uint4 u; bf16x8 b; } x;
    x.u = v;
    return x.b;
}

// ---------------------------------------------------------------------------
// init / graph preprocessing
// ---------------------------------------------------------------------------

__global__ void k_zero(int* __restrict__ a, int* __restrict__ b, int n) {
    int i = blockIdx.x * blockDim.x + threadIdx.x;
    if (i < n) { a[i] = 0; b[i] = 0; }
}

__device__ __forceinline__ int clamp_node(int v) {
    return v < 0 ? 0 : (v >= N_NODES ? N_NODES - 1 : v);
}

__global__ void k_count(const int* __restrict__ ei, int* __restrict__ counts) {
    int e = blockIdx.x * blockDim.x + threadIdx.x;
    if (e < N_EDGES) {
        int dst = clamp_node(ei[N_EDGES + e]);
        atomicAdd(&counts[dst], 1);
    }
}

__global__ void k_dinv(const int* __restrict__ counts, float* __restrict__ dinv) {
    int i = blockIdx.x * blockDim.x + threadIdx.x;
    if (i < N_NODES) {
        dinv[i] = rsqrtf((float)counts[i] + 1.0f);
    }
}

__global__ __launch_bounds__(256) void k_scan1(const int* __restrict__ counts,
                                               int* __restrict__ part,
                                               int* __restrict__ bsum) {
    __shared__ int s[256];
    const int tid = threadIdx.x;
    const int i = blockIdx.x * 256 + tid;
    int v = (i < N_NODES) ? counts[i] : 0;
    s[tid] = v;
    __syncthreads();
    for (int off = 1; off < 256; off <<= 1) {
        int t = (tid >= off) ? s[tid - off] : 0;
        __syncthreads();
        s[tid] += t;
        __syncthreads();
    }
    if (i < N_NODES) part[i] = s[tid];
    if (tid == 255) bsum[blockIdx.x] = s[255];
}

__global__ __launch_bounds__(256) void k_scan2(const int* __restrict__ bsum,
                                               int* __restrict__ boff) {
    __shared__ int s[256];
    const int tid = threadIdx.x;
    int v = (tid < SCAN_BLOCKS) ? bsum[tid] : 0;
    s[tid] = v;
    __syncthreads();
    for (int off = 1; off < 256; off <<= 1) {
        int t = (tid >= off) ? s[tid - off] : 0;
        __syncthreads();
        s[tid] += t;
        __syncthreads();
    }
    if (tid < SCAN_BLOCKS) boff[tid] = s[tid] - v;
}

__global__ __launch_bounds__(256) void k_scan3(const int* __restrict__ part,
                                               const int* __restrict__ counts,
                                               const int* __restrict__ boff,
                                               int* __restrict__ offsets) {
    const int i = blockIdx.x * 256 + threadIdx.x;
    if (i < N_NODES) offsets[i] = part[i] - counts[i] + boff[blockIdx.x];
    if (i == 0) offsets[N_NODES] = N_EDGES;
}

__global__ void k_fill(const int* __restrict__ ei, const int* __restrict__ offsets,
                       int* __restrict__ cursor, int* __restrict__ csr) {
    int e = blockIdx.x * blockDim.x + threadIdx.x;
    if (e < N_EDGES) {
        int src = clamp_node(ei[e]);
        int dst = clamp_node(ei[N_EDGES + e]);
        int pos = atomicAdd(&cursor[dst], 1);
        int slot = offsets[dst] + pos;
        if (slot < N_EDGES) csr[slot] = src;
    }
}

// ---------------------------------------------------------------------------
// Weight prep: split weights into bf16 hi/lo, MFMA-fragment layout.
// Frag index within a section: f = kf*8 + nf (kf-major batches contiguous).
// Lane l of frag f holds W[k=kf*32+(l>>4)*8+j][n=nf*16+(l&15)] j=0..7 as
// bf16x8 (4 u32 hi then 4 u32 lo). Entry = 8 u32/lane, frag = 2 KB.
// Sections: 0,1 = W1 N-halves; 2,3 = W2 K-halves; 4 = fcW1; 5 = fcW2.
// ---------------------------------------------------------------------------

__global__ __launch_bounds__(64) void k_prep(const float* __restrict__ W1,
                                             const float* __restrict__ W2,
                                             const float* __restrict__ fcW1,
                                             const float* __restrict__ fcW2,
                                             unsigned int* __restrict__ ftab) {
    int bx = blockIdx.x;          // 0..191
    int s = bx >> 5, f = bx & 31;
    int kf = f >> 3, nf = f & 7;
    int l = threadIdx.x;
    const float* src; int ld, roff, coff;
    switch (s) {
        case 0:  src = W1;   ld = 256; roff = 0;   coff = 0;   break;
        case 1:  src = W1;   ld = 256; roff = 0;   coff = 128; break;
        case 2:  src = W2;   ld = 128; roff = 0;   coff = 0;   break;
        case 3:  src = W2;   ld = 128; roff = 128; coff = 0;   break;
        case 4:  src = fcW1; ld = 128; roff = 0;   coff = 0;   break;
        default: src = fcW2; ld = 128; roff = 0;   coff = 0;   break;
    }
    int col = coff + nf * 16 + (l & 15);
    int krow = roff + kf * 32 + (l >> 4) * 8;
    unsigned int hp[4], lp[4];
#pragma unroll
    for (int p = 0; p < 4; ++p) {
        float a0 = src[(size_t)(krow + 2 * p) * ld + col];
        float a1 = src[(size_t)(krow + 2 * p + 1) * ld + col];
        unsigned int h0 = __float_as_uint(a0) & 0xFFFF0000u;
        unsigned int h1 = __float_as_uint(a1) & 0xFFFF0000u;
        float r0 = a0 - __uint_as_float(h0);
        float r1 = a1 - __uint_as_float(h1);
        hp[p] = (h0 >> 16) | h1;
        lp[p] = ((__float_as_uint(r0) & 0xFFFF0000u) >> 16) |
                (__float_as_uint(r1) & 0xFFFF0000u);
    }
    unsigned int* dst = ftab + ((size_t)bx * 64 + l) * 8;
    *reinterpret_cast<uint4*>(dst)     = make_uint4(hp[0], hp[1], hp[2], hp[3]);
    *reinterpret_cast<uint4*>(dst + 4) = make_uint4(lp[0], lp[1], lp[2], lp[3]);
}

// ---------------------------------------------------------------------------
// Propagation (unchanged)
// ---------------------------------------------------------------------------

template <bool HAS_BIAS, bool RELU>
__global__ __launch_bounds__(256) void k_prop(const float* __restrict__ in,
                                              float* __restrict__ out,
                                              const float* __restrict__ dinv,
                                              const int* __restrict__ offsets,
                                              const int* __restrict__ csr,
                                              const float* __restrict__ bias) {
    const int wave = threadIdx.x >> 6;
    const int lane = threadIdx.x & 63;
    const int node = blockIdx.x * 4 + wave;
    if (node >= N_NODES) return;

    const float di = dinv[node];
    float2 sv = reinterpret_cast<const float2*>(in + (size_t)node * C128)[lane];
    float acc0 = di * sv.x;
    float acc1 = di * sv.y;

    int e = offsets[node];
    const int eend = offsets[node + 1];
    for (; e + 4 <= eend; e += 4) {
        int s0 = csr[e + 0], s1 = csr[e + 1], s2 = csr[e + 2], s3 = csr[e + 3];
        float w0 = dinv[s0], w1 = dinv[s1], w2 = dinv[s2], w3 = dinv[s3];
        float2 v0 = reinterpret_cast<const float2*>(in + (size_t)s0 * C128)[lane];
        float2 v1 = reinterpret_cast<const float2*>(in + (size_t)s1 * C128)[lane];
        float2 v2 = reinterpret_cast<const float2*>(in + (size_t)s2 * C128)[lane];
        float2 v3 = reinterpret_cast<const float2*>(in + (size_t)s3 * C128)[lane];
        acc0 = fmaf(w0, v0.x, acc0); acc1 = fmaf(w0, v0.y, acc1);
        acc0 = fmaf(w1, v1.x, acc0); acc1 = fmaf(w1, v1.y, acc1);
        acc0 = fmaf(w2, v2.x, acc0); acc1 = fmaf(w2, v2.y, acc1);
        acc0 = fmaf(w3, v3.x, acc0); acc1 = fmaf(w3, v3.y, acc1);
    }
    for (; e < eend; ++e) {
        int s = csr[e];
        float w = dinv[s];
        float2 v = reinterpret_cast<const float2*>(in + (size_t)s * C128)[lane];
        acc0 = fmaf(w, v.x, acc0);
        acc1 = fmaf(w, v.y, acc1);
    }

    float o0 = di * acc0;
    float o1 = di * acc1;
    if (HAS_BIAS) {
        o0 += bias[2 * lane + 0];
        o1 += bias[2 * lane + 1];
    }
    if (RELU) {
        o0 = fmaxf(o0, 0.0f);
        o1 = fmaxf(o1, 0.0f);
    }
    reinterpret_cast<float2*>(out + (size_t)node * C128)[lane] = make_float2(o0, o1);
}

// ---------------------------------------------------------------------------
// Fused 2-GEMM chain, transposed MFMA products, no LDS, no barriers.
// Each wave owns TWO 16-row m-tiles (32 rows); per kf the 8 weight frag-pairs
// are batch-loaded into registers (16 independent dwordx4) then consumed by
// 48 MFMAs -> latency amortized over 6 MFMAs per 32 B/lane of weights.
// In-place C==A safe per-lane (MFMA column j depends only on arg1 column j).
// ACT1: 1 = relu, 2 = elu
// ---------------------------------------------------------------------------

template <int NHALF, int ACT1, bool FINAL_BIAS>
__global__ __launch_bounds__(256, 2) void k_fused(
        const float* __restrict__ A,
        const unsigned int* __restrict__ ftabW1,
        const unsigned int* __restrict__ ftabW2,
        const float* __restrict__ b1v,
        const float* __restrict__ b2v,
        float* __restrict__ C, int M) {
    const int tid = threadIdx.x;
    const int wave = tid >> 6, l = tid & 63;
    const int l15 = l & 15, l4 = l >> 4;
    const int m_base = blockIdx.x * 128 + wave * 32;

    int r0 = m_base + l15;
    int r1 = m_base + 16 + l15;
    const float* arow0 = A + (size_t)(r0 < M ? r0 : M - 1) * 128;
    const float* arow1 = A + (size_t)(r1 < M ? r1 : M - 1) * 128;

    f32x4 accQ[2][8] = {};

    for (int half = 0; half < NHALF; ++half) {
        const unsigned int* w1base = ftabW1 + (size_t)half * (32 * 64 * 8);
        const unsigned int* w2base = ftabW2 + (size_t)half * (32 * 64 * 8);

        // ---------------- phase 1: accH[t] = W1h^T · A[t]^T ----------------
        f32x4 accH[2][8] = {};
#pragma unroll
        for (int kf = 0; kf < 4; ++kf) {
            // batch-load 8 weight frag-pairs (contiguous 16 KB)
            uint4 wh[8], wl[8];
#pragma unroll
            for (int nf = 0; nf < 8; ++nf) {
                const uint4* fp = reinterpret_cast<const uint4*>(
                    w1base + (((size_t)(kf * 8 + nf)) * 64 + l) * 8);
                wh[nf] = fp[0];
                wl[nf] = fp[1];
            }
            // load + split A frags for this kf, both tiles
            bf16x8 ahi[2], alo[2];
#pragma unroll
            for (int t = 0; t < 2; ++t) {
                const float* ap = (t == 0 ? arow0 : arow1) + kf * 32 + l4 * 8;
                float4 v0 = *reinterpret_cast<const float4*>(ap);
                float4 v1 = *reinterpret_cast<const float4*>(ap + 4);
                float av[8] = {v0.x, v0.y, v0.z, v0.w, v1.x, v1.y, v1.z, v1.w};
                unsigned int hp[4], lp[4];
#pragma unroll
                for (int p = 0; p < 4; ++p) {
                    float a0 = av[2 * p], a1 = av[2 * p + 1];
                    unsigned int h0 = __float_as_uint(a0) & 0xFFFF0000u;
                    unsigned int h1 = __float_as_uint(a1) & 0xFFFF0000u;
                    float q0 = a0 - __uint_as_float(h0);
                    float q1 = a1 - __uint_as_float(h1);
                    hp[p] = (h0 >> 16) | h1;
                    lp[p] = ((__float_as_uint(q0) & 0xFFFF0000u) >> 16) |
                            (__float_as_uint(q1) & 0xFFFF0000u);
                }
                if (t == 0) { ahi[0] = pack_bf16x8(hp[0], hp[1], hp[2], hp[3]);
                              alo[0] = pack_bf16x8(lp[0], lp[1], lp[2], lp[3]); }
                else        { ahi[1] = pack_bf16x8(hp[0], hp[1], hp[2], hp[3]);
                              alo[1] = pack_bf16x8(lp[0], lp[1], lp[2], lp[3]); }
            }
#pragma unroll
            for (int nf = 0; nf < 8; ++nf) {
                bf16x8 whi = as_bf16x8(wh[nf]);
                bf16x8 wlo = as_bf16x8(wl[nf]);
#pragma unroll
                for (int t = 0; t < 2; ++t) {
                    accH[t][nf] = __builtin_amdgcn_mfma_f32_16x16x32_bf16(whi, ahi[t], accH[t][nf], 0, 0, 0);
                    accH[t][nf] = __builtin_amdgcn_mfma_f32_16x16x32_bf16(whi, alo[t], accH[t][nf], 0, 0, 0);
                    accH[t][nf] = __builtin_amdgcn_mfma_f32_16x16x32_bf16(wlo, ahi[t], accH[t][nf], 0, 0, 0);
                }
            }
        }

        // ---- epilogue 1: bias + act, split-pack (hi | lo<<16) ----
        unsigned int hpk[2][8][4];
#pragma unroll
        for (int nf = 0; nf < 8; ++nf) {
            const float4 bb = *reinterpret_cast<const float4*>(
                b1v + half * 128 + nf * 16 + l4 * 4);
            const float bbv[4] = {bb.x, bb.y, bb.z, bb.w};
#pragma unroll
            for (int t = 0; t < 2; ++t) {
#pragma unroll
                for (int reg = 0; reg < 4; ++reg) {
                    float v = accH[t][nf][reg] + bbv[reg];
                    if (ACT1 == 1) v = fmaxf(v, 0.0f);
                    else           v = v > 0.0f ? v : (expf(v) - 1.0f);
                    unsigned int vh = __float_as_uint(v) & 0xFFFF0000u;
                    float rr = v - __uint_as_float(vh);
                    hpk[t][nf][reg] = (vh >> 16) | (__float_as_uint(rr) & 0xFFFF0000u);
                }
            }
        }

        // ---------------- phase 2: accQ[t] += W2h^T · H[t]^T ----------------
#pragma unroll
        for (int kf = 0; kf < 4; ++kf) {
            uint4 wh[8], wl[8];
#pragma unroll
            for (int nf = 0; nf < 8; ++nf) {
                const uint4* fp = reinterpret_cast<const uint4*>(
                    w2base + (((size_t)(kf * 8 + nf)) * 64 + l) * 8);
                wh[nf] = fp[0];
                wl[nf] = fp[1];
            }
            // build H^T fragments via 16-lane shuffles, per tile
            bf16x8 bh[2], bl[2];
#pragma unroll
            for (int t = 0; t < 2; ++t) {
                unsigned int got[8];
#pragma unroll
                for (int je = 0; je < 8; ++je) {
                    int srcLane = ((l4 & 1) * 2 + (je >> 2)) * 16 + l15;
                    unsigned int g0 = __shfl(hpk[t][2 * kf][je & 3], srcLane, 64);
                    unsigned int g1 = __shfl(hpk[t][2 * kf + 1][je & 3], srcLane, 64);
                    got[je] = (l4 & 2) ? g1 : g0;
                }
                unsigned int hh[4], gg[4];
#pragma unroll
                for (int p = 0; p < 4; ++p) {
                    hh[p] = (got[2 * p] & 0xFFFFu) | (got[2 * p + 1] << 16);
                    gg[p] = (got[2 * p] >> 16) | (got[2 * p + 1] & 0xFFFF0000u);
                }
                bh[t] = pack_bf16x8(hh[0], hh[1], hh[2], hh[3]);
                bl[t] = pack_bf16x8(gg[0], gg[1], gg[2], gg[3]);
            }
#pragma unroll
            for (int nf = 0; nf < 8; ++nf) {
                bf16x8 whi = as_bf16x8(wh[nf]);
                bf16x8 wlo = as_bf16x8(wl[nf]);
#pragma unroll
                for (int t = 0; t < 2; ++t) {
                    accQ[t][nf] = __builtin_amdgcn_mfma_f32_16x16x32_bf16(whi, bh[t], accQ[t][nf], 0, 0, 0);
                    accQ[t][nf] = __builtin_amdgcn_mfma_f32_16x16x32_bf16(whi, bl[t], accQ[t][nf], 0, 0, 0);
                    accQ[t][nf] = __builtin_amdgcn_mfma_f32_16x16x32_bf16(wlo, bh[t], accQ[t][nf], 0, 0, 0);
                }
            }
        }
    }

    // ---- final epilogue: C[r][nf*16 + l4*4 .. +3] = accQ (+b2) ----
#pragma unroll
    for (int t = 0; t < 2; ++t) {
        int r = (t == 0) ? r0 : r1;
        if (r < M) {
#pragma unroll
            for (int nf = 0; nf < 8; ++nf) {
                float4 v;
                v.x = accQ[t][nf][0]; v.y = accQ[t][nf][1];
                v.z = accQ[t][nf][2]; v.w = accQ[t][nf][3];
                if (FINAL_BIAS) {
                    const float4 bb = *reinterpret_cast<const float4*>(
                        b2v + nf * 16 + l4 * 4);
                    v.x += bb.x; v.y += bb.y; v.z += bb.z; v.w += bb.w;
                }
                *reinterpret_cast<float4*>(C + (size_t)r * 128 + nf * 16 + l4 * 4) = v;
            }
        }
    }
}

// ---------------------------------------------------------------------------
// launch
// ---------------------------------------------------------------------------

extern "C" void kernel_launch(void* const* d_in, const int* in_sizes, int n_in,
                              void* d_out, int out_size, void* d_ws, size_t ws_size,
                              hipStream_t stream) {
    const float* x    = (const float*)d_in[0];
    const int*   ei   = (const int*)d_in[1];   // int64 in reference -> int32 from harness
    const float* W1   = (const float*)d_in[2]; // [128,256]
    const float* b1   = (const float*)d_in[3];
    const float* W2   = (const float*)d_in[4]; // [256,128]
    const float* b2   = (const float*)d_in[5];
    const float* fcW1 = (const float*)d_in[6]; // [128,128]
    const float* fcb1 = (const float*)d_in[7];
    const float* fcW2 = (const float*)d_in[8]; // [128,128]
    const float* fcb2 = (const float*)d_in[9];
    float* out        = (float*)d_out;         // [N,128], also ping-pong scratch

    char* ws = (char*)d_ws;
    size_t off = 0;
    auto alloc = [&](size_t bytes) {
        void* p = ws + off;
        off += (bytes + 255) & ~(size_t)255;
        return p;
    };
    int*   counts  = (int*)alloc(N_NODES * sizeof(int));
    int*   cursor  = (int*)alloc(N_NODES * sizeof(int));
    int*   part    = (int*)alloc(N_NODES * sizeof(int));
    int*   bsum    = (int*)alloc(SCAN_BLOCKS * sizeof(int));
    int*   boff    = (int*)alloc(SCAN_BLOCKS * sizeof(int));
    int*   offsets = (int*)alloc((N_NODES + 1) * sizeof(int));
    int*   csr     = (int*)alloc(N_EDGES * sizeof(int));
    float* dinv    = (float*)alloc(N_NODES * sizeof(float));
    unsigned int* ftab = (unsigned int*)alloc((size_t)192 * 64 * 8 * sizeof(unsigned int));
    float* Q       = (float*)alloc((size_t)N_NODES * 128 * sizeof(float));
    (void)ws_size; (void)n_in; (void)in_sizes; (void)out_size;

    const unsigned int SEC = 32 * 64 * 8;  // u32 per section

    // graph preprocessing + weight prep
    k_zero<<<(N_NODES + 255) / 256, 256, 0, stream>>>(counts, cursor, N_NODES);
    k_prep<<<192, 64, 0, stream>>>(W1, W2, fcW1, fcW2, ftab);
    k_count<<<(N_EDGES + 255) / 256, 256, 0, stream>>>(ei, counts);
    k_dinv<<<(N_NODES + 255) / 256, 256, 0, stream>>>(counts, dinv);
    k_scan1<<<SCAN_BLOCKS, 256, 0, stream>>>(counts, part, bsum);
    k_scan2<<<1, 256, 0, stream>>>(bsum, boff);
    k_scan3<<<SCAN_BLOCKS, 256, 0, stream>>>(part, counts, boff, offsets);
    k_fill<<<(N_EDGES + 255) / 256, 256, 0, stream>>>(ei, offsets, cursor, csr);

    const int prop_grid = (N_NODES + 3) / 4;
    const int gm = (N_NODES + 127) / 128;  // 391 (128 rows per block, 32 per wave)

    // layer 1 propagate (pre-GEMM side): agg = prop(x) -> out (scratch)
    k_prop<false, false><<<prop_grid, 256, 0, stream>>>(x, out, dinv, offsets, csr, nullptr);

    // fused mid: Q = relu(agg@W1 + b1) @ W2
    k_fused<2, 1, false><<<gm, 256, 0, stream>>>(out, ftab, ftab + 2 * SEC,
                                                 b1, nullptr, Q, N_NODES);

    // layer 2 propagate: z = relu(prop(Q) + b2) -> out
    k_prop<true, true><<<prop_grid, 256, 0, stream>>>(Q, out, dinv, offsets, csr, b2);

    // fused head (in-place): out = elu(out@fcW1 + fcb1) @ fcW2 + fcb2
    k_fused<1, 2, true><<<gm, 256, 0, stream>>>(out, ftab + 4 * SEC, ftab + 5 * SEC,
                                                fcb1, fcb2, out, N_NODES);
}

// Round 8
// 278.593 us; speedup vs baseline: 1.6685x; 1.0910x over previous
//
#include <hip/hip_runtime.h>
#include <hip/hip_bf16.h>
#include <cstdint>

#define N_NODES 50000
#define N_EDGES 800000
#define C128 128
#define SCAN_BLOCKS ((N_NODES + 255) / 256)   // 196

typedef __attribute__((ext_vector_type(8))) short bf16x8;
typedef __attribute__((ext_vector_type(4))) float f32x4;
typedef unsigned int u32;

__device__ __forceinline__ bf16x8 pack_bf16x8(u32 a, u32 b, u32 c, u32 d) {
    union { u32 u[4]; bf16x8 v; } x;
    x.u[0] = a; x.u[1] = b; x.u[2] = c; x.u[3] = d;
    return x.v;
}

__device__ __forceinline__ bf16x8 as_bf16x8(uint4 v) {
    union { uint4 u; bf16x8 b; } x;
    x.u = v;
    return x.b;
}

// async global->LDS, 16B per lane: lds dest = base + lane*16, g is per-lane.
__device__ __forceinline__ void stage16(const u32* g, u32* lds) {
    __builtin_amdgcn_global_load_lds(
        (const __attribute__((address_space(1))) u32*)g,
        (__attribute__((address_space(3))) u32*)lds, 16, 0, 0);
}

// ---------------------------------------------------------------------------
// init / graph preprocessing
// ---------------------------------------------------------------------------

__global__ void k_zero(int* __restrict__ a, int* __restrict__ b, int n) {
    int i = blockIdx.x * blockDim.x + threadIdx.x;
    if (i < n) { a[i] = 0; b[i] = 0; }
}

__device__ __forceinline__ int clamp_node(int v) {
    return v < 0 ? 0 : (v >= N_NODES ? N_NODES - 1 : v);
}

__global__ void k_count(const int* __restrict__ ei, int* __restrict__ counts) {
    int e = blockIdx.x * blockDim.x + threadIdx.x;
    if (e < N_EDGES) {
        int dst = clamp_node(ei[N_EDGES + e]);
        atomicAdd(&counts[dst], 1);
    }
}

__global__ void k_dinv(const int* __restrict__ counts, float* __restrict__ dinv) {
    int i = blockIdx.x * blockDim.x + threadIdx.x;
    if (i < N_NODES) {
        dinv[i] = rsqrtf((float)counts[i] + 1.0f);
    }
}

__global__ __launch_bounds__(256) void k_scan1(const int* __restrict__ counts,
                                               int* __restrict__ part,
                                               int* __restrict__ bsum) {
    __shared__ int s[256];
    const int tid = threadIdx.x;
    const int i = blockIdx.x * 256 + tid;
    int v = (i < N_NODES) ? counts[i] : 0;
    s[tid] = v;
    __syncthreads();
    for (int off = 1; off < 256; off <<= 1) {
        int t = (tid >= off) ? s[tid - off] : 0;
        __syncthreads();
        s[tid] += t;
        __syncthreads();
    }
    if (i < N_NODES) part[i] = s[tid];
    if (tid == 255) bsum[blockIdx.x] = s[255];
}

__global__ __launch_bounds__(256) void k_scan2(const int* __restrict__ bsum,
                                               int* __restrict__ boff) {
    __shared__ int s[256];
    const int tid = threadIdx.x;
    int v = (tid < SCAN_BLOCKS) ? bsum[tid] : 0;
    s[tid] = v;
    __syncthreads();
    for (int off = 1; off < 256; off <<= 1) {
        int t = (tid >= off) ? s[tid - off] : 0;
        __syncthreads();
        s[tid] += t;
        __syncthreads();
    }
    if (tid < SCAN_BLOCKS) boff[tid] = s[tid] - v;
}

__global__ __launch_bounds__(256) void k_scan3(const int* __restrict__ part,
                                               const int* __restrict__ counts,
                                               const int* __restrict__ boff,
                                               int* __restrict__ offsets) {
    const int i = blockIdx.x * 256 + threadIdx.x;
    if (i < N_NODES) offsets[i] = part[i] - counts[i] + boff[blockIdx.x];
    if (i == 0) offsets[N_NODES] = N_EDGES;
}

__global__ void k_fill(const int* __restrict__ ei, const int* __restrict__ offsets,
                       int* __restrict__ cursor, int* __restrict__ csr) {
    int e = blockIdx.x * blockDim.x + threadIdx.x;
    if (e < N_EDGES) {
        int src = clamp_node(ei[e]);
        int dst = clamp_node(ei[N_EDGES + e]);
        int pos = atomicAdd(&cursor[dst], 1);
        int slot = offsets[dst] + pos;
        if (slot < N_EDGES) csr[slot] = src;
    }
}

// ---------------------------------------------------------------------------
// Weight prep: split weights into bf16 hi/lo, MFMA-fragment layout, arranged
// for linear LDS staging. Frag f = kf*8+nf inside a 64 KB section occupies
// 512 u32: [f*512 + l*4 .. +3] = hi uint4 of lane l; [f*512+256+l*4] = lo.
// kf-batch (8 frags, 16 KB) is contiguous -> staged with global_load_lds.
// Lane l of frag holds W[k=kf*32+(l>>4)*8+j][n=nf*16+(l&15)], j=0..7.
// Sections: 0,1 = W1 N-halves; 2,3 = W2 K-halves; 4 = fcW1; 5 = fcW2.
// ---------------------------------------------------------------------------

__global__ __launch_bounds__(64) void k_prep(const float* __restrict__ W1,
                                             const float* __restrict__ W2,
                                             const float* __restrict__ fcW1,
                                             const float* __restrict__ fcW2,
                                             u32* __restrict__ ftab) {
    int bx = blockIdx.x;          // 0..191
    int s = bx >> 5, f = bx & 31;
    int kf = f >> 3, nf = f & 7;
    int l = threadIdx.x;
    const float* src; int ld, roff, coff;
    switch (s) {
        case 0:  src = W1;   ld = 256; roff = 0;   coff = 0;   break;
        case 1:  src = W1;   ld = 256; roff = 0;   coff = 128; break;
        case 2:  src = W2;   ld = 128; roff = 0;   coff = 0;   break;
        case 3:  src = W2;   ld = 128; roff = 128; coff = 0;   break;
        case 4:  src = fcW1; ld = 128; roff = 0;   coff = 0;   break;
        default: src = fcW2; ld = 128; roff = 0;   coff = 0;   break;
    }
    int col = coff + nf * 16 + (l & 15);
    int krow = roff + kf * 32 + (l >> 4) * 8;
    u32 hp[4], lp[4];
#pragma unroll
    for (int p = 0; p < 4; ++p) {
        float a0 = src[(size_t)(krow + 2 * p) * ld + col];
        float a1 = src[(size_t)(krow + 2 * p + 1) * ld + col];
        u32 h0 = __float_as_uint(a0) & 0xFFFF0000u;
        u32 h1 = __float_as_uint(a1) & 0xFFFF0000u;
        float r0 = a0 - __uint_as_float(h0);
        float r1 = a1 - __uint_as_float(h1);
        hp[p] = (h0 >> 16) | h1;
        lp[p] = ((__float_as_uint(r0) & 0xFFFF0000u) >> 16) |
                (__float_as_uint(r1) & 0xFFFF0000u);
    }
    u32* dst = ftab + (size_t)bx * 512;
    *reinterpret_cast<uint4*>(dst + 4 * l)       = make_uint4(hp[0], hp[1], hp[2], hp[3]);
    *reinterpret_cast<uint4*>(dst + 256 + 4 * l) = make_uint4(lp[0], lp[1], lp[2], lp[3]);
}

// ---------------------------------------------------------------------------
// Propagation (unchanged)
// ---------------------------------------------------------------------------

template <bool HAS_BIAS, bool RELU>
__global__ __launch_bounds__(256) void k_prop(const float* __restrict__ in,
                                              float* __restrict__ out,
                                              const float* __restrict__ dinv,
                                              const int* __restrict__ offsets,
                                              const int* __restrict__ csr,
                                              const float* __restrict__ bias) {
    const int wave = threadIdx.x >> 6;
    const int lane = threadIdx.x & 63;
    const int node = blockIdx.x * 4 + wave;
    if (node >= N_NODES) return;

    const float di = dinv[node];
    float2 sv = reinterpret_cast<const float2*>(in + (size_t)node * C128)[lane];
    float acc0 = di * sv.x;
    float acc1 = di * sv.y;

    int e = offsets[node];
    const int eend = offsets[node + 1];
    for (; e + 4 <= eend; e += 4) {
        int s0 = csr[e + 0], s1 = csr[e + 1], s2 = csr[e + 2], s3 = csr[e + 3];
        float w0 = dinv[s0], w1 = dinv[s1], w2 = dinv[s2], w3 = dinv[s3];
        float2 v0 = reinterpret_cast<const float2*>(in + (size_t)s0 * C128)[lane];
        float2 v1 = reinterpret_cast<const float2*>(in + (size_t)s1 * C128)[lane];
        float2 v2 = reinterpret_cast<const float2*>(in + (size_t)s2 * C128)[lane];
        float2 v3 = reinterpret_cast<const float2*>(in + (size_t)s3 * C128)[lane];
        acc0 = fmaf(w0, v0.x, acc0); acc1 = fmaf(w0, v0.y, acc1);
        acc0 = fmaf(w1, v1.x, acc0); acc1 = fmaf(w1, v1.y, acc1);
        acc0 = fmaf(w2, v2.x, acc0); acc1 = fmaf(w2, v2.y, acc1);
        acc0 = fmaf(w3, v3.x, acc0); acc1 = fmaf(w3, v3.y, acc1);
    }
    for (; e < eend; ++e) {
        int s = csr[e];
        float w = dinv[s];
        float2 v = reinterpret_cast<const float2*>(in + (size_t)s * C128)[lane];
        acc0 = fmaf(w, v.x, acc0);
        acc1 = fmaf(w, v.y, acc1);
    }

    float o0 = di * acc0;
    float o1 = di * acc1;
    if (HAS_BIAS) {
        o0 += bias[2 * lane + 0];
        o1 += bias[2 * lane + 1];
    }
    if (RELU) {
        o0 = fmaxf(o0, 0.0f);
        o1 = fmaxf(o1, 0.0f);
    }
    reinterpret_cast<float2*>(out + (size_t)node * C128)[lane] = make_float2(o0, o1);
}

// ---------------------------------------------------------------------------
// Fused 2-GEMM chain, transposed MFMA products, LDS-staged weights.
// Block = 4 waves x 16 rows = 64 rows. Per kf-step the 16 KB weight batch is
// staged to LDS (double-buffered, global_load_lds, shared by all 4 waves):
//   prologue STAGE(0); barrier
//   step s: STAGE(s+1, buf^1); ds_read buf -> 24 MFMA; barrier; flip
// Steps: NHALF * {phase1 kf0..3, phase2 kf0..3}. H^T stays in registers,
// phase2 A-operand fragments built via 16-lane shuffles (validated r6/r7).
// In-place C==A safe: each wave reads/writes only its own 16 rows.
// ACT1: 1 = relu, 2 = elu
// ---------------------------------------------------------------------------

template <int NHALF, int ACT1, bool FINAL_BIAS>
__global__ __launch_bounds__(256) void k_fused(
        const float* __restrict__ A,
        const u32* __restrict__ ftabW1,
        const u32* __restrict__ ftabW2,
        const float* __restrict__ b1v,
        const float* __restrict__ b2v,
        float* __restrict__ C, int M) {
    __shared__ u32 lds_w[2][4096];   // 2 x 16 KB kf-batches

    const int tid = threadIdx.x;
    const int wave = tid >> 6, l = tid & 63;
    const int l15 = l & 15, l4 = l >> 4;
    const int r = blockIdx.x * 64 + wave * 16 + l15;
    const float* arow = A + (size_t)(r < M ? r : M - 1) * 128;

    const int NSTEP = NHALF * 8;

    // stage one 16 KB kf-batch: each wave moves its 4 KB quarter (4 x 1 KB)
    auto stepbase = [&](int s) -> const u32* {
        int half = (NHALF == 2) ? (s >> 3) : 0;
        int phase = (s >> 2) & 1;
        int kf = s & 3;
        const u32* sec = phase ? ftabW2 : ftabW1;
        return sec + (size_t)half * 16384 + kf * 4096;
    };
    auto stage_batch = [&](int s, int buf) {
        const u32* g = stepbase(s) + wave * 1024 + 4 * l;
        u32* lb = &lds_w[buf][wave * 1024];
        stage16(g, lb);
        stage16(g + 256, lb + 256);
        stage16(g + 512, lb + 512);
        stage16(g + 768, lb + 768);
    };

    f32x4 accQ[8] = {};
    int buf = 0;

    stage_batch(0, 0);
    __syncthreads();

    for (int half = 0; half < NHALF; ++half) {
        // ---------------- phase 1: accH = W1h^T · A^T ----------------
        f32x4 accH[8] = {};
#pragma unroll
        for (int kf = 0; kf < 4; ++kf) {
            int s = half * 8 + kf;
            if (s + 1 < NSTEP) stage_batch(s + 1, buf ^ 1);

            // A fragment for this kf, split hi/lo
            const float* ap = arow + kf * 32 + l4 * 8;
            float4 v0 = *reinterpret_cast<const float4*>(ap);
            float4 v1 = *reinterpret_cast<const float4*>(ap + 4);
            float av[8] = {v0.x, v0.y, v0.z, v0.w, v1.x, v1.y, v1.z, v1.w};
            u32 hp[4], lp[4];
#pragma unroll
            for (int p = 0; p < 4; ++p) {
                float a0 = av[2 * p], a1 = av[2 * p + 1];
                u32 h0 = __float_as_uint(a0) & 0xFFFF0000u;
                u32 h1 = __float_as_uint(a1) & 0xFFFF0000u;
                float q0 = a0 - __uint_as_float(h0);
                float q1 = a1 - __uint_as_float(h1);
                hp[p] = (h0 >> 16) | h1;
                lp[p] = ((__float_as_uint(q0) & 0xFFFF0000u) >> 16) |
                        (__float_as_uint(q1) & 0xFFFF0000u);
            }
            bf16x8 ahi = pack_bf16x8(hp[0], hp[1], hp[2], hp[3]);
            bf16x8 alo = pack_bf16x8(lp[0], lp[1], lp[2], lp[3]);

            const u32* lb = lds_w[buf];
#pragma unroll
            for (int nf = 0; nf < 8; ++nf) {
                const u32* fb = lb + nf * 512;
                bf16x8 whi = as_bf16x8(*reinterpret_cast<const uint4*>(fb + 4 * l));
                bf16x8 wlo = as_bf16x8(*reinterpret_cast<const uint4*>(fb + 256 + 4 * l));
                accH[nf] = __builtin_amdgcn_mfma_f32_16x16x32_bf16(whi, ahi, accH[nf], 0, 0, 0);
                accH[nf] = __builtin_amdgcn_mfma_f32_16x16x32_bf16(whi, alo, accH[nf], 0, 0, 0);
                accH[nf] = __builtin_amdgcn_mfma_f32_16x16x32_bf16(wlo, ahi, accH[nf], 0, 0, 0);
            }
            __syncthreads();
            buf ^= 1;
        }

        // ---- epilogue 1: bias + act, split-pack (hi | lo<<16) ----
        u32 hpk[8][4];
#pragma unroll
        for (int nf = 0; nf < 8; ++nf) {
            const float4 bb = *reinterpret_cast<const float4*>(
                b1v + half * 128 + nf * 16 + l4 * 4);
            const float bbv[4] = {bb.x, bb.y, bb.z, bb.w};
#pragma unroll
            for (int reg = 0; reg < 4; ++reg) {
                float v = accH[nf][reg] + bbv[reg];
                if (ACT1 == 1) v = fmaxf(v, 0.0f);
                else           v = v > 0.0f ? v : (expf(v) - 1.0f);
                u32 vh = __float_as_uint(v) & 0xFFFF0000u;
                float rr = v - __uint_as_float(vh);
                hpk[nf][reg] = (vh >> 16) | (__float_as_uint(rr) & 0xFFFF0000u);
            }
        }

        // ---------------- phase 2: accQ += W2h^T · H^T ----------------
#pragma unroll
        for (int kf = 0; kf < 4; ++kf) {
            int s = half * 8 + 4 + kf;
            if (s + 1 < NSTEP) stage_batch(s + 1, buf ^ 1);

            // build H^T fragment via 16-lane shuffles
            u32 got[8];
#pragma unroll
            for (int je = 0; je < 8; ++je) {
                int srcLane = ((l4 & 1) * 2 + (je >> 2)) * 16 + l15;
                u32 g0 = __shfl(hpk[2 * kf][je & 3], srcLane, 64);
                u32 g1 = __shfl(hpk[2 * kf + 1][je & 3], srcLane, 64);
                got[je] = (l4 & 2) ? g1 : g0;
            }
            u32 hh[4], gg[4];
#pragma unroll
            for (int p = 0; p < 4; ++p) {
                hh[p] = (got[2 * p] & 0xFFFFu) | (got[2 * p + 1] << 16);
                gg[p] = (got[2 * p] >> 16) | (got[2 * p + 1] & 0xFFFF0000u);
            }
            bf16x8 bh = pack_bf16x8(hh[0], hh[1], hh[2], hh[3]);
            bf16x8 bl = pack_bf16x8(gg[0], gg[1], gg[2], gg[3]);

            const u32* lb = lds_w[buf];
#pragma unroll
            for (int nf = 0; nf < 8; ++nf) {
                const u32* fb = lb + nf * 512;
                bf16x8 whi = as_bf16x8(*reinterpret_cast<const uint4*>(fb + 4 * l));
                bf16x8 wlo = as_bf16x8(*reinterpret_cast<const uint4*>(fb + 256 + 4 * l));
                accQ[nf] = __builtin_amdgcn_mfma_f32_16x16x32_bf16(whi, bh, accQ[nf], 0, 0, 0);
                accQ[nf] = __builtin_amdgcn_mfma_f32_16x16x32_bf16(whi, bl, accQ[nf], 0, 0, 0);
                accQ[nf] = __builtin_amdgcn_mfma_f32_16x16x32_bf16(wlo, bh, accQ[nf], 0, 0, 0);
            }
            __syncthreads();
            buf ^= 1;
        }
    }

    // ---- final epilogue: C[r][nf*16 + l4*4 .. +3] = accQ (+b2) ----
    if (r < M) {
#pragma unroll
        for (int nf = 0; nf < 8; ++nf) {
            float4 v;
            v.x = accQ[nf][0]; v.y = accQ[nf][1];
            v.z = accQ[nf][2]; v.w = accQ[nf][3];
            if (FINAL_BIAS) {
                const float4 bb = *reinterpret_cast<const float4*>(b2v + nf * 16 + l4 * 4);
                v.x += bb.x; v.y += bb.y; v.z += bb.z; v.w += bb.w;
            }
            *reinterpret_cast<float4*>(C + (size_t)r * 128 + nf * 16 + l4 * 4) = v;
        }
    }
}

// ---------------------------------------------------------------------------
// launch
// ---------------------------------------------------------------------------

extern "C" void kernel_launch(void* const* d_in, const int* in_sizes, int n_in,
                              void* d_out, int out_size, void* d_ws, size_t ws_size,
                              hipStream_t stream) {
    const float* x    = (const float*)d_in[0];
    const int*   ei   = (const int*)d_in[1];   // int64 in reference -> int32 from harness
    const float* W1   = (const float*)d_in[2]; // [128,256]
    const float* b1   = (const float*)d_in[3];
    const float* W2   = (const float*)d_in[4]; // [256,128]
    const float* b2   = (const float*)d_in[5];
    const float* fcW1 = (const float*)d_in[6]; // [128,128]
    const float* fcb1 = (const float*)d_in[7];
    const float* fcW2 = (const float*)d_in[8]; // [128,128]
    const float* fcb2 = (const float*)d_in[9];
    float* out        = (float*)d_out;         // [N,128], also ping-pong scratch

    char* ws = (char*)d_ws;
    size_t off = 0;
    auto alloc = [&](size_t bytes) {
        void* p = ws + off;
        off += (bytes + 255) & ~(size_t)255;
        return p;
    };
    int*   counts  = (int*)alloc(N_NODES * sizeof(int));
    int*   cursor  = (int*)alloc(N_NODES * sizeof(int));
    int*   part    = (int*)alloc(N_NODES * sizeof(int));
    int*   bsum    = (int*)alloc(SCAN_BLOCKS * sizeof(int));
    int*   boff    = (int*)alloc(SCAN_BLOCKS * sizeof(int));
    int*   offsets = (int*)alloc((N_NODES + 1) * sizeof(int));
    int*   csr     = (int*)alloc(N_EDGES * sizeof(int));
    float* dinv    = (float*)alloc(N_NODES * sizeof(float));
    u32*   ftab    = (u32*)alloc((size_t)192 * 512 * sizeof(u32));
    float* Q       = (float*)alloc((size_t)N_NODES * 128 * sizeof(float));
    (void)ws_size; (void)n_in; (void)in_sizes; (void)out_size;

    const u32 SEC = 16384;  // u32 per 64 KB section

    // graph preprocessing + weight prep
    k_zero<<<(N_NODES + 255) / 256, 256, 0, stream>>>(counts, cursor, N_NODES);
    k_prep<<<192, 64, 0, stream>>>(W1, W2, fcW1, fcW2, ftab);
    k_count<<<(N_EDGES + 255) / 256, 256, 0, stream>>>(ei, counts);
    k_dinv<<<(N_NODES + 255) / 256, 256, 0, stream>>>(counts, dinv);
    k_scan1<<<SCAN_BLOCKS, 256, 0, stream>>>(counts, part, bsum);
    k_scan2<<<1, 256, 0, stream>>>(bsum, boff);
    k_scan3<<<SCAN_BLOCKS, 256, 0, stream>>>(part, counts, boff, offsets);
    k_fill<<<(N_EDGES + 255) / 256, 256, 0, stream>>>(ei, offsets, cursor, csr);

    const int prop_grid = (N_NODES + 3) / 4;
    const int gm = (N_NODES + 63) / 64;   // 782 (64 rows per block, 16 per wave)

    // layer 1 propagate (pre-GEMM side): agg = prop(x) -> out (scratch)
    k_prop<false, false><<<prop_grid, 256, 0, stream>>>(x, out, dinv, offsets, csr, nullptr);

    // fused mid: Q = relu(agg@W1 + b1) @ W2
    k_fused<2, 1, false><<<gm, 256, 0, stream>>>(out, ftab, ftab + 2 * SEC,
                                                 b1, nullptr, Q, N_NODES);

    // layer 2 propagate: z = relu(prop(Q) + b2) -> out
    k_prop<true, true><<<prop_grid, 256, 0, stream>>>(Q, out, dinv, offsets, csr, b2);

    // fused head (in-place): out = elu(out@fcW1 + fcb1) @ fcW2 + fcb2
    k_fused<1, 2, true><<<gm, 256, 0, stream>>>(out, ftab + 4 * SEC, ftab + 5 * SEC,
                                                fcb1, fcb2, out, N_NODES);
}

// Round 9
// 275.435 us; speedup vs baseline: 1.6876x; 1.0115x over previous
//
#include <hip/hip_runtime.h>
#include <hip/hip_bf16.h>
#include <cstdint>

#define N_NODES 50000
#define N_EDGES 800000
#define C128 128
#define SCAN_BLOCKS ((N_NODES + 255) / 256)   // 196

typedef __attribute__((ext_vector_type(8))) short bf16x8;
typedef __attribute__((ext_vector_type(4))) float f32x4;
typedef unsigned int u32;

__device__ __forceinline__ bf16x8 pack_bf16x8(u32 a, u32 b, u32 c, u32 d) {
    union { u32 u[4]; bf16x8 v; } x;
    x.u[0] = a; x.u[1] = b; x.u[2] = c; x.u[3] = d;
    return x.v;
}

__device__ __forceinline__ bf16x8 as_bf16x8(uint4 v) {
    union { uint4 u; bf16x8 b; } x;
    x.u = v;
    return x.b;
}

// async global->LDS, 16B per lane: lds dest = base + lane*16, g is per-lane.
__device__ __forceinline__ void stage16(const u32* g, u32* lds) {
    __builtin_amdgcn_global_load_lds(
        (const __attribute__((address_space(1))) u32*)g,
        (__attribute__((address_space(3))) u32*)lds, 16, 0, 0);
}

// ---------------------------------------------------------------------------
// init / graph preprocessing
// ---------------------------------------------------------------------------

__global__ void k_zero(int* __restrict__ a, int* __restrict__ b, int n) {
    int i = blockIdx.x * blockDim.x + threadIdx.x;
    if (i < n) { a[i] = 0; b[i] = 0; }
}

__device__ __forceinline__ int clamp_node(int v) {
    return v < 0 ? 0 : (v >= N_NODES ? N_NODES - 1 : v);
}

__global__ void k_count(const int* __restrict__ ei, int* __restrict__ counts) {
    int e = blockIdx.x * blockDim.x + threadIdx.x;
    if (e < N_EDGES) {
        int dst = clamp_node(ei[N_EDGES + e]);
        atomicAdd(&counts[dst], 1);
    }
}

__global__ void k_dinv(const int* __restrict__ counts, float* __restrict__ dinv) {
    int i = blockIdx.x * blockDim.x + threadIdx.x;
    if (i < N_NODES) {
        dinv[i] = rsqrtf((float)counts[i] + 1.0f);
    }
}

__global__ __launch_bounds__(256) void k_scan1(const int* __restrict__ counts,
                                               int* __restrict__ part,
                                               int* __restrict__ bsum) {
    __shared__ int s[256];
    const int tid = threadIdx.x;
    const int i = blockIdx.x * 256 + tid;
    int v = (i < N_NODES) ? counts[i] : 0;
    s[tid] = v;
    __syncthreads();
    for (int off = 1; off < 256; off <<= 1) {
        int t = (tid >= off) ? s[tid - off] : 0;
        __syncthreads();
        s[tid] += t;
        __syncthreads();
    }
    if (i < N_NODES) part[i] = s[tid];
    if (tid == 255) bsum[blockIdx.x] = s[255];
}

__global__ __launch_bounds__(256) void k_scan2(const int* __restrict__ bsum,
                                               int* __restrict__ boff) {
    __shared__ int s[256];
    const int tid = threadIdx.x;
    int v = (tid < SCAN_BLOCKS) ? bsum[tid] : 0;
    s[tid] = v;
    __syncthreads();
    for (int off = 1; off < 256; off <<= 1) {
        int t = (tid >= off) ? s[tid - off] : 0;
        __syncthreads();
        s[tid] += t;
        __syncthreads();
    }
    if (tid < SCAN_BLOCKS) boff[tid] = s[tid] - v;
}

__global__ __launch_bounds__(256) void k_scan3(const int* __restrict__ part,
                                               const int* __restrict__ counts,
                                               const int* __restrict__ boff,
                                               int* __restrict__ offsets) {
    const int i = blockIdx.x * 256 + threadIdx.x;
    if (i < N_NODES) offsets[i] = part[i] - counts[i] + boff[blockIdx.x];
    if (i == 0) offsets[N_NODES] = N_EDGES;
}

__global__ void k_fill(const int* __restrict__ ei, const int* __restrict__ offsets,
                       int* __restrict__ cursor, int* __restrict__ csr) {
    int e = blockIdx.x * blockDim.x + threadIdx.x;
    if (e < N_EDGES) {
        int src = clamp_node(ei[e]);
        int dst = clamp_node(ei[N_EDGES + e]);
        int pos = atomicAdd(&cursor[dst], 1);
        int slot = offsets[dst] + pos;
        if (slot < N_EDGES) csr[slot] = src;
    }
}

// ---------------------------------------------------------------------------
// Weight prep: split weights into bf16 hi/lo, MFMA-fragment layout, arranged
// for linear LDS staging. Frag f = kf*8+nf inside a 64 KB section occupies
// 512 u32: [f*512 + l*4 .. +3] = hi uint4 of lane l; [f*512+256+l*4] = lo.
// kf-batch (8 frags, 16 KB) is contiguous -> staged with global_load_lds.
// Lane l of frag holds W[k=kf*32+(l>>4)*8+j][n=nf*16+(l&15)], j=0..7.
// Sections: 0,1 = W1 N-halves; 2,3 = W2 K-halves; 4 = fcW1; 5 = fcW2.
// ---------------------------------------------------------------------------

__global__ __launch_bounds__(64) void k_prep(const float* __restrict__ W1,
                                             const float* __restrict__ W2,
                                             const float* __restrict__ fcW1,
                                             const float* __restrict__ fcW2,
                                             u32* __restrict__ ftab) {
    int bx = blockIdx.x;          // 0..191
    int s = bx >> 5, f = bx & 31;
    int kf = f >> 3, nf = f & 7;
    int l = threadIdx.x;
    const float* src; int ld, roff, coff;
    switch (s) {
        case 0:  src = W1;   ld = 256; roff = 0;   coff = 0;   break;
        case 1:  src = W1;   ld = 256; roff = 0;   coff = 128; break;
        case 2:  src = W2;   ld = 128; roff = 0;   coff = 0;   break;
        case 3:  src = W2;   ld = 128; roff = 128; coff = 0;   break;
        case 4:  src = fcW1; ld = 128; roff = 0;   coff = 0;   break;
        default: src = fcW2; ld = 128; roff = 0;   coff = 0;   break;
    }
    int col = coff + nf * 16 + (l & 15);
    int krow = roff + kf * 32 + (l >> 4) * 8;
    u32 hp[4], lp[4];
#pragma unroll
    for (int p = 0; p < 4; ++p) {
        float a0 = src[(size_t)(krow + 2 * p) * ld + col];
        float a1 = src[(size_t)(krow + 2 * p + 1) * ld + col];
        u32 h0 = __float_as_uint(a0) & 0xFFFF0000u;
        u32 h1 = __float_as_uint(a1) & 0xFFFF0000u;
        float r0 = a0 - __uint_as_float(h0);
        float r1 = a1 - __uint_as_float(h1);
        hp[p] = (h0 >> 16) | h1;
        lp[p] = ((__float_as_uint(r0) & 0xFFFF0000u) >> 16) |
                (__float_as_uint(r1) & 0xFFFF0000u);
    }
    u32* dst = ftab + (size_t)bx * 512;
    *reinterpret_cast<uint4*>(dst + 4 * l)       = make_uint4(hp[0], hp[1], hp[2], hp[3]);
    *reinterpret_cast<uint4*>(dst + 256 + 4 * l) = make_uint4(lp[0], lp[1], lp[2], lp[3]);
}

// ---------------------------------------------------------------------------
// Propagation: out[i] = dinv[i]*( sum_{s in N(i)} dinv[s]*in[s] + dinv[i]*in[i] )
// (+bias)(relu).  TWO nodes per wave (lanes 0-31 / 32-63), float4 per lane:
// per wave-instruction 2 rows (1 KB) move; 4-edge unroll -> 8 rows in flight.
// ---------------------------------------------------------------------------

template <bool HAS_BIAS, bool RELU>
__global__ __launch_bounds__(256) void k_prop(const float* __restrict__ in,
                                              float* __restrict__ out,
                                              const float* __restrict__ dinv,
                                              const int* __restrict__ offsets,
                                              const int* __restrict__ csr,
                                              const float* __restrict__ bias) {
    const int wave = threadIdx.x >> 6;
    const int lane = threadIdx.x & 63;
    const int half = lane >> 5;
    const int lc   = lane & 31;          // float4 channel group
    const int node = (blockIdx.x * 4 + wave) * 2 + half;
    if (node >= N_NODES) return;

    const float4* __restrict__ inp = reinterpret_cast<const float4*>(in);
    const float di = dinv[node];
    float4 sv = inp[(size_t)node * 32 + lc];
    float ax = di * sv.x, ay = di * sv.y, az = di * sv.z, aw = di * sv.w;

    int e = offsets[node];
    const int eend = offsets[node + 1];
    for (; e + 4 <= eend; e += 4) {
        int s0 = csr[e + 0], s1 = csr[e + 1], s2 = csr[e + 2], s3 = csr[e + 3];
        float w0 = dinv[s0], w1 = dinv[s1], w2 = dinv[s2], w3 = dinv[s3];
        float4 v0 = inp[(size_t)s0 * 32 + lc];
        float4 v1 = inp[(size_t)s1 * 32 + lc];
        float4 v2 = inp[(size_t)s2 * 32 + lc];
        float4 v3 = inp[(size_t)s3 * 32 + lc];
        ax = fmaf(w0, v0.x, ax); ay = fmaf(w0, v0.y, ay);
        az = fmaf(w0, v0.z, az); aw = fmaf(w0, v0.w, aw);
        ax = fmaf(w1, v1.x, ax); ay = fmaf(w1, v1.y, ay);
        az = fmaf(w1, v1.z, az); aw = fmaf(w1, v1.w, aw);
        ax = fmaf(w2, v2.x, ax); ay = fmaf(w2, v2.y, ay);
        az = fmaf(w2, v2.z, az); aw = fmaf(w2, v2.w, aw);
        ax = fmaf(w3, v3.x, ax); ay = fmaf(w3, v3.y, ay);
        az = fmaf(w3, v3.z, az); aw = fmaf(w3, v3.w, aw);
    }
    for (; e < eend; ++e) {
        int s = csr[e];
        float w = dinv[s];
        float4 v = inp[(size_t)s * 32 + lc];
        ax = fmaf(w, v.x, ax); ay = fmaf(w, v.y, ay);
        az = fmaf(w, v.z, az); aw = fmaf(w, v.w, aw);
    }

    float4 o;
    o.x = di * ax; o.y = di * ay; o.z = di * az; o.w = di * aw;
    if (HAS_BIAS) {
        float4 bb = reinterpret_cast<const float4*>(bias)[lc];
        o.x += bb.x; o.y += bb.y; o.z += bb.z; o.w += bb.w;
    }
    if (RELU) {
        o.x = fmaxf(o.x, 0.0f); o.y = fmaxf(o.y, 0.0f);
        o.z = fmaxf(o.z, 0.0f); o.w = fmaxf(o.w, 0.0f);
    }
    reinterpret_cast<float4*>(out)[(size_t)node * 32 + lc] = o;
}

// ---------------------------------------------------------------------------
// Fused 2-GEMM chain, transposed MFMA products, LDS-staged weights.
// Block = 4 waves x 16 rows = 64 rows. Per kf-step the 16 KB weight batch is
// staged to LDS (double-buffered, global_load_lds, shared by all 4 waves).
// (unchanged from round 8)
// ---------------------------------------------------------------------------

template <int NHALF, int ACT1, bool FINAL_BIAS>
__global__ __launch_bounds__(256) void k_fused(
        const float* __restrict__ A,
        const u32* __restrict__ ftabW1,
        const u32* __restrict__ ftabW2,
        const float* __restrict__ b1v,
        const float* __restrict__ b2v,
        float* __restrict__ C, int M) {
    __shared__ u32 lds_w[2][4096];   // 2 x 16 KB kf-batches

    const int tid = threadIdx.x;
    const int wave = tid >> 6, l = tid & 63;
    const int l15 = l & 15, l4 = l >> 4;
    const int r = blockIdx.x * 64 + wave * 16 + l15;
    const float* arow = A + (size_t)(r < M ? r : M - 1) * 128;

    const int NSTEP = NHALF * 8;

    auto stepbase = [&](int s) -> const u32* {
        int half = (NHALF == 2) ? (s >> 3) : 0;
        int phase = (s >> 2) & 1;
        int kf = s & 3;
        const u32* sec = phase ? ftabW2 : ftabW1;
        return sec + (size_t)half * 16384 + kf * 4096;
    };
    auto stage_batch = [&](int s, int buf) {
        const u32* g = stepbase(s) + wave * 1024 + 4 * l;
        u32* lb = &lds_w[buf][wave * 1024];
        stage16(g, lb);
        stage16(g + 256, lb + 256);
        stage16(g + 512, lb + 512);
        stage16(g + 768, lb + 768);
    };

    f32x4 accQ[8] = {};
    int buf = 0;

    stage_batch(0, 0);
    __syncthreads();

    for (int half = 0; half < NHALF; ++half) {
        // ---------------- phase 1: accH = W1h^T · A^T ----------------
        f32x4 accH[8] = {};
#pragma unroll
        for (int kf = 0; kf < 4; ++kf) {
            int s = half * 8 + kf;
            if (s + 1 < NSTEP) stage_batch(s + 1, buf ^ 1);

            const float* ap = arow + kf * 32 + l4 * 8;
            float4 v0 = *reinterpret_cast<const float4*>(ap);
            float4 v1 = *reinterpret_cast<const float4*>(ap + 4);
            float av[8] = {v0.x, v0.y, v0.z, v0.w, v1.x, v1.y, v1.z, v1.w};
            u32 hp[4], lp[4];
#pragma unroll
            for (int p = 0; p < 4; ++p) {
                float a0 = av[2 * p], a1 = av[2 * p + 1];
                u32 h0 = __float_as_uint(a0) & 0xFFFF0000u;
                u32 h1 = __float_as_uint(a1) & 0xFFFF0000u;
                float q0 = a0 - __uint_as_float(h0);
                float q1 = a1 - __uint_as_float(h1);
                hp[p] = (h0 >> 16) | h1;
                lp[p] = ((__float_as_uint(q0) & 0xFFFF0000u) >> 16) |
                        (__float_as_uint(q1) & 0xFFFF0000u);
            }
            bf16x8 ahi = pack_bf16x8(hp[0], hp[1], hp[2], hp[3]);
            bf16x8 alo = pack_bf16x8(lp[0], lp[1], lp[2], lp[3]);

            const u32* lb = lds_w[buf];
#pragma unroll
            for (int nf = 0; nf < 8; ++nf) {
                const u32* fb = lb + nf * 512;
                bf16x8 whi = as_bf16x8(*reinterpret_cast<const uint4*>(fb + 4 * l));
                bf16x8 wlo = as_bf16x8(*reinterpret_cast<const uint4*>(fb + 256 + 4 * l));
                accH[nf] = __builtin_amdgcn_mfma_f32_16x16x32_bf16(whi, ahi, accH[nf], 0, 0, 0);
                accH[nf] = __builtin_amdgcn_mfma_f32_16x16x32_bf16(whi, alo, accH[nf], 0, 0, 0);
                accH[nf] = __builtin_amdgcn_mfma_f32_16x16x32_bf16(wlo, ahi, accH[nf], 0, 0, 0);
            }
            __syncthreads();
            buf ^= 1;
        }

        // ---- epilogue 1: bias + act, split-pack (hi | lo<<16) ----
        u32 hpk[8][4];
#pragma unroll
        for (int nf = 0; nf < 8; ++nf) {
            const float4 bb = *reinterpret_cast<const float4*>(
                b1v + half * 128 + nf * 16 + l4 * 4);
            const float bbv[4] = {bb.x, bb.y, bb.z, bb.w};
#pragma unroll
            for (int reg = 0; reg < 4; ++reg) {
                float v = accH[nf][reg] + bbv[reg];
                if (ACT1 == 1) v = fmaxf(v, 0.0f);
                else           v = v > 0.0f ? v : (expf(v) - 1.0f);
                u32 vh = __float_as_uint(v) & 0xFFFF0000u;
                float rr = v - __uint_as_float(vh);
                hpk[nf][reg] = (vh >> 16) | (__float_as_uint(rr) & 0xFFFF0000u);
            }
        }

        // ---------------- phase 2: accQ += W2h^T · H^T ----------------
#pragma unroll
        for (int kf = 0; kf < 4; ++kf) {
            int s = half * 8 + 4 + kf;
            if (s + 1 < NSTEP) stage_batch(s + 1, buf ^ 1);

            u32 got[8];
#pragma unroll
            for (int je = 0; je < 8; ++je) {
                int srcLane = ((l4 & 1) * 2 + (je >> 2)) * 16 + l15;
                u32 g0 = __shfl(hpk[2 * kf][je & 3], srcLane, 64);
                u32 g1 = __shfl(hpk[2 * kf + 1][je & 3], srcLane, 64);
                got[je] = (l4 & 2) ? g1 : g0;
            }
            u32 hh[4], gg[4];
#pragma unroll
            for (int p = 0; p < 4; ++p) {
                hh[p] = (got[2 * p] & 0xFFFFu) | (got[2 * p + 1] << 16);
                gg[p] = (got[2 * p] >> 16) | (got[2 * p + 1] & 0xFFFF0000u);
            }
            bf16x8 bh = pack_bf16x8(hh[0], hh[1], hh[2], hh[3]);
            bf16x8 bl = pack_bf16x8(gg[0], gg[1], gg[2], gg[3]);

            const u32* lb = lds_w[buf];
#pragma unroll
            for (int nf = 0; nf < 8; ++nf) {
                const u32* fb = lb + nf * 512;
                bf16x8 whi = as_bf16x8(*reinterpret_cast<const uint4*>(fb + 4 * l));
                bf16x8 wlo = as_bf16x8(*reinterpret_cast<const uint4*>(fb + 256 + 4 * l));
                accQ[nf] = __builtin_amdgcn_mfma_f32_16x16x32_bf16(whi, bh, accQ[nf], 0, 0, 0);
                accQ[nf] = __builtin_amdgcn_mfma_f32_16x16x32_bf16(whi, bl, accQ[nf], 0, 0, 0);
                accQ[nf] = __builtin_amdgcn_mfma_f32_16x16x32_bf16(wlo, bh, accQ[nf], 0, 0, 0);
            }
            __syncthreads();
            buf ^= 1;
        }
    }

    // ---- final epilogue: C[r][nf*16 + l4*4 .. +3] = accQ (+b2) ----
    if (r < M) {
#pragma unroll
        for (int nf = 0; nf < 8; ++nf) {
            float4 v;
            v.x = accQ[nf][0]; v.y = accQ[nf][1];
            v.z = accQ[nf][2]; v.w = accQ[nf][3];
            if (FINAL_BIAS) {
                const float4 bb = *reinterpret_cast<const float4*>(b2v + nf * 16 + l4 * 4);
                v.x += bb.x; v.y += bb.y; v.z += bb.z; v.w += bb.w;
            }
            *reinterpret_cast<float4*>(C + (size_t)r * 128 + nf * 16 + l4 * 4) = v;
        }
    }
}

// ---------------------------------------------------------------------------
// launch
// ---------------------------------------------------------------------------

extern "C" void kernel_launch(void* const* d_in, const int* in_sizes, int n_in,
                              void* d_out, int out_size, void* d_ws, size_t ws_size,
                              hipStream_t stream) {
    const float* x    = (const float*)d_in[0];
    const int*   ei   = (const int*)d_in[1];   // int64 in reference -> int32 from harness
    const float* W1   = (const float*)d_in[2]; // [128,256]
    const float* b1   = (const float*)d_in[3];
    const float* W2   = (const float*)d_in[4]; // [256,128]
    const float* b2   = (const float*)d_in[5];
    const float* fcW1 = (const float*)d_in[6]; // [128,128]
    const float* fcb1 = (const float*)d_in[7];
    const float* fcW2 = (const float*)d_in[8]; // [128,128]
    const float* fcb2 = (const float*)d_in[9];
    float* out        = (float*)d_out;         // [N,128], also ping-pong scratch

    char* ws = (char*)d_ws;
    size_t off = 0;
    auto alloc = [&](size_t bytes) {
        void* p = ws + off;
        off += (bytes + 255) & ~(size_t)255;
        return p;
    };
    int*   counts  = (int*)alloc(N_NODES * sizeof(int));
    int*   cursor  = (int*)alloc(N_NODES * sizeof(int));
    int*   part    = (int*)alloc(N_NODES * sizeof(int));
    int*   bsum    = (int*)alloc(SCAN_BLOCKS * sizeof(int));
    int*   boff    = (int*)alloc(SCAN_BLOCKS * sizeof(int));
    int*   offsets = (int*)alloc((N_NODES + 1) * sizeof(int));
    int*   csr     = (int*)alloc(N_EDGES * sizeof(int));
    float* dinv    = (float*)alloc(N_NODES * sizeof(float));
    u32*   ftab    = (u32*)alloc((size_t)192 * 512 * sizeof(u32));
    float* Q       = (float*)alloc((size_t)N_NODES * 128 * sizeof(float));
    (void)ws_size; (void)n_in; (void)in_sizes; (void)out_size;

    const u32 SEC = 16384;  // u32 per 64 KB section

    // graph preprocessing + weight prep
    k_zero<<<(N_NODES + 255) / 256, 256, 0, stream>>>(counts, cursor, N_NODES);
    k_prep<<<192, 64, 0, stream>>>(W1, W2, fcW1, fcW2, ftab);
    k_count<<<(N_EDGES + 255) / 256, 256, 0, stream>>>(ei, counts);
    k_dinv<<<(N_NODES + 255) / 256, 256, 0, stream>>>(counts, dinv);
    k_scan1<<<SCAN_BLOCKS, 256, 0, stream>>>(counts, part, bsum);
    k_scan2<<<1, 256, 0, stream>>>(bsum, boff);
    k_scan3<<<SCAN_BLOCKS, 256, 0, stream>>>(part, counts, boff, offsets);
    k_fill<<<(N_EDGES + 255) / 256, 256, 0, stream>>>(ei, offsets, cursor, csr);

    const int prop_grid = (N_NODES + 7) / 8;  // 6250: 8 nodes/block, 2 per wave
    const int gm = (N_NODES + 63) / 64;       // 782 (64 rows per block, 16 per wave)

    // layer 1 propagate (pre-GEMM side): agg = prop(x) -> out (scratch)
    k_prop<false, false><<<prop_grid, 256, 0, stream>>>(x, out, dinv, offsets, csr, nullptr);

    // fused mid: Q = relu(agg@W1 + b1) @ W2
    k_fused<2, 1, false><<<gm, 256, 0, stream>>>(out, ftab, ftab + 2 * SEC,
                                                 b1, nullptr, Q, N_NODES);

    // layer 2 propagate: z = relu(prop(Q) + b2) -> out
    k_prop<true, true><<<prop_grid, 256, 0, stream>>>(Q, out, dinv, offsets, csr, b2);

    // fused head (in-place): out = elu(out@fcW1 + fcb1) @ fcW2 + fcb2
    k_fused<1, 2, true><<<gm, 256, 0, stream>>>(out, ftab + 4 * SEC, ftab + 5 * SEC,
                                                fcb1, fcb2, out, N_NODES);
}

// Round 10
// 240.040 us; speedup vs baseline: 1.9364x; 1.1475x over previous
//
#include <hip/hip_runtime.h>
#include <hip/hip_bf16.h>
#include <cstdint>

#define N_NODES 50000
#define N_EDGES 800000
#define C128 128
#define SCAN_BLOCKS ((N_NODES + 255) / 256)   // 196

typedef __attribute__((ext_vector_type(8))) short bf16x8;
typedef __attribute__((ext_vector_type(4))) float f32x4;
typedef unsigned int u32;

__device__ __forceinline__ bf16x8 pack_bf16x8(u32 a, u32 b, u32 c, u32 d) {
    union { u32 u[4]; bf16x8 v; } x;
    x.u[0] = a; x.u[1] = b; x.u[2] = c; x.u[3] = d;
    return x.v;
}

__device__ __forceinline__ bf16x8 as_bf16x8(uint4 v) {
    union { uint4 u; bf16x8 b; } x;
    x.u = v;
    return x.b;
}

// round-to-nearest-even f32 -> bf16 (returned in low 16 bits)
__device__ __forceinline__ u32 rne_bf16(float x) {
    u32 u = __float_as_uint(x);
    return (u + 0x7FFFu + ((u >> 16) & 1u)) >> 16;
}

// async global->LDS, 16B per lane: lds dest = base + lane*16, g is per-lane.
__device__ __forceinline__ void stage16(const u32* g, u32* lds) {
    __builtin_amdgcn_global_load_lds(
        (const __attribute__((address_space(1))) u32*)g,
        (__attribute__((address_space(3))) u32*)lds, 16, 0, 0);
}

// ---------------------------------------------------------------------------
// init / graph preprocessing
// ---------------------------------------------------------------------------

__global__ void k_zero(int* __restrict__ a, int* __restrict__ b, int n) {
    int i = blockIdx.x * blockDim.x + threadIdx.x;
    if (i < n) { a[i] = 0; b[i] = 0; }
}

__device__ __forceinline__ int clamp_node(int v) {
    return v < 0 ? 0 : (v >= N_NODES ? N_NODES - 1 : v);
}

__global__ void k_count(const int* __restrict__ ei, int* __restrict__ counts) {
    int e = blockIdx.x * blockDim.x + threadIdx.x;
    if (e < N_EDGES) {
        int dst = clamp_node(ei[N_EDGES + e]);
        atomicAdd(&counts[dst], 1);
    }
}

__global__ void k_dinv(const int* __restrict__ counts, float* __restrict__ dinv) {
    int i = blockIdx.x * blockDim.x + threadIdx.x;
    if (i < N_NODES) {
        dinv[i] = rsqrtf((float)counts[i] + 1.0f);
    }
}

// xs[i][c] = bf16_rne( dinv[i] * x[i][c] ), 4 channels per thread
__global__ __launch_bounds__(256) void k_xscale(const float* __restrict__ x,
                                                const float* __restrict__ dinv,
                                                u32* __restrict__ xs /*uint2 area*/) {
    int idx = blockIdx.x * 256 + threadIdx.x;      // one float4 group
    if (idx < N_NODES * 32) {
        int node = idx >> 5;
        float di = dinv[node];
        float4 v = reinterpret_cast<const float4*>(x)[idx];
        u32 w0 = rne_bf16(v.x * di) | (rne_bf16(v.y * di) << 16);
        u32 w1 = rne_bf16(v.z * di) | (rne_bf16(v.w * di) << 16);
        reinterpret_cast<uint2*>(xs)[idx] = make_uint2(w0, w1);
    }
}

__global__ __launch_bounds__(256) void k_scan1(const int* __restrict__ counts,
                                               int* __restrict__ part,
                                               int* __restrict__ bsum) {
    __shared__ int s[256];
    const int tid = threadIdx.x;
    const int i = blockIdx.x * 256 + tid;
    int v = (i < N_NODES) ? counts[i] : 0;
    s[tid] = v;
    __syncthreads();
    for (int off = 1; off < 256; off <<= 1) {
        int t = (tid >= off) ? s[tid - off] : 0;
        __syncthreads();
        s[tid] += t;
        __syncthreads();
    }
    if (i < N_NODES) part[i] = s[tid];
    if (tid == 255) bsum[blockIdx.x] = s[255];
}

__global__ __launch_bounds__(256) void k_scan2(const int* __restrict__ bsum,
                                               int* __restrict__ boff) {
    __shared__ int s[256];
    const int tid = threadIdx.x;
    int v = (tid < SCAN_BLOCKS) ? bsum[tid] : 0;
    s[tid] = v;
    __syncthreads();
    for (int off = 1; off < 256; off <<= 1) {
        int t = (tid >= off) ? s[tid - off] : 0;
        __syncthreads();
        s[tid] += t;
        __syncthreads();
    }
    if (tid < SCAN_BLOCKS) boff[tid] = s[tid] - v;
}

__global__ __launch_bounds__(256) void k_scan3(const int* __restrict__ part,
                                               const int* __restrict__ counts,
                                               const int* __restrict__ boff,
                                               int* __restrict__ offsets) {
    const int i = blockIdx.x * 256 + threadIdx.x;
    if (i < N_NODES) offsets[i] = part[i] - counts[i] + boff[blockIdx.x];
    if (i == 0) offsets[N_NODES] = N_EDGES;
}

__global__ void k_fill(const int* __restrict__ ei, const int* __restrict__ offsets,
                       int* __restrict__ cursor, int* __restrict__ csr) {
    int e = blockIdx.x * blockDim.x + threadIdx.x;
    if (e < N_EDGES) {
        int src = clamp_node(ei[e]);
        int dst = clamp_node(ei[N_EDGES + e]);
        int pos = atomicAdd(&cursor[dst], 1);
        int slot = offsets[dst] + pos;
        if (slot < N_EDGES) csr[slot] = src;
    }
}

// ---------------------------------------------------------------------------
// Weight prep (unchanged from round 8)
// ---------------------------------------------------------------------------

__global__ __launch_bounds__(64) void k_prep(const float* __restrict__ W1,
                                             const float* __restrict__ W2,
                                             const float* __restrict__ fcW1,
                                             const float* __restrict__ fcW2,
                                             u32* __restrict__ ftab) {
    int bx = blockIdx.x;          // 0..191
    int s = bx >> 5, f = bx & 31;
    int kf = f >> 3, nf = f & 7;
    int l = threadIdx.x;
    const float* src; int ld, roff, coff;
    switch (s) {
        case 0:  src = W1;   ld = 256; roff = 0;   coff = 0;   break;
        case 1:  src = W1;   ld = 256; roff = 0;   coff = 128; break;
        case 2:  src = W2;   ld = 128; roff = 0;   coff = 0;   break;
        case 3:  src = W2;   ld = 128; roff = 128; coff = 0;   break;
        case 4:  src = fcW1; ld = 128; roff = 0;   coff = 0;   break;
        default: src = fcW2; ld = 128; roff = 0;   coff = 0;   break;
    }
    int col = coff + nf * 16 + (l & 15);
    int krow = roff + kf * 32 + (l >> 4) * 8;
    u32 hp[4], lp[4];
#pragma unroll
    for (int p = 0; p < 4; ++p) {
        float a0 = src[(size_t)(krow + 2 * p) * ld + col];
        float a1 = src[(size_t)(krow + 2 * p + 1) * ld + col];
        u32 h0 = __float_as_uint(a0) & 0xFFFF0000u;
        u32 h1 = __float_as_uint(a1) & 0xFFFF0000u;
        float r0 = a0 - __uint_as_float(h0);
        float r1 = a1 - __uint_as_float(h1);
        hp[p] = (h0 >> 16) | h1;
        lp[p] = ((__float_as_uint(r0) & 0xFFFF0000u) >> 16) |
                (__float_as_uint(r1) & 0xFFFF0000u);
    }
    u32* dst = ftab + (size_t)bx * 512;
    *reinterpret_cast<uint4*>(dst + 4 * l)       = make_uint4(hp[0], hp[1], hp[2], hp[3]);
    *reinterpret_cast<uint4*>(dst + 256 + 4 * l) = make_uint4(lp[0], lp[1], lp[2], lp[3]);
}

// ---------------------------------------------------------------------------
// Propagation over pre-scaled bf16 features:
//   out[i] = dinv[i] * ( sum_{s in N(i)} xs[s] + xs[i] )  (+bias)(relu), f32 out
// xs rows are 256 B. Two nodes per wave; lane covers 4 bf16 channels (uint2).
// No per-edge dinv gather; plain adds.
// ---------------------------------------------------------------------------

template <bool HAS_BIAS, bool RELU>
__global__ __launch_bounds__(256) void k_prop(const u32* __restrict__ xs,
                                              float* __restrict__ out,
                                              const float* __restrict__ dinv,
                                              const int* __restrict__ offsets,
                                              const int* __restrict__ csr,
                                              const float* __restrict__ bias) {
    const int wave = threadIdx.x >> 6;
    const int lane = threadIdx.x & 63;
    const int half = lane >> 5;
    const int lc   = lane & 31;          // 4-channel group
    const int node = (blockIdx.x * 4 + wave) * 2 + half;
    if (node >= N_NODES) return;

    const uint2* __restrict__ xp = reinterpret_cast<const uint2*>(xs);
    const float di = dinv[node];

    uint2 sv = xp[(size_t)node * 32 + lc];
    float ax = __uint_as_float(sv.x << 16);
    float ay = __uint_as_float(sv.x & 0xFFFF0000u);
    float az = __uint_as_float(sv.y << 16);
    float aw = __uint_as_float(sv.y & 0xFFFF0000u);

    int e = offsets[node];
    const int eend = offsets[node + 1];
    for (; e + 4 <= eend; e += 4) {
        int s0 = csr[e + 0], s1 = csr[e + 1], s2 = csr[e + 2], s3 = csr[e + 3];
        uint2 v0 = xp[(size_t)s0 * 32 + lc];
        uint2 v1 = xp[(size_t)s1 * 32 + lc];
        uint2 v2 = xp[(size_t)s2 * 32 + lc];
        uint2 v3 = xp[(size_t)s3 * 32 + lc];
        ax += __uint_as_float(v0.x << 16);
        ay += __uint_as_float(v0.x & 0xFFFF0000u);
        az += __uint_as_float(v0.y << 16);
        aw += __uint_as_float(v0.y & 0xFFFF0000u);
        ax += __uint_as_float(v1.x << 16);
        ay += __uint_as_float(v1.x & 0xFFFF0000u);
        az += __uint_as_float(v1.y << 16);
        aw += __uint_as_float(v1.y & 0xFFFF0000u);
        ax += __uint_as_float(v2.x << 16);
        ay += __uint_as_float(v2.x & 0xFFFF0000u);
        az += __uint_as_float(v2.y << 16);
        aw += __uint_as_float(v2.y & 0xFFFF0000u);
        ax += __uint_as_float(v3.x << 16);
        ay += __uint_as_float(v3.x & 0xFFFF0000u);
        az += __uint_as_float(v3.y << 16);
        aw += __uint_as_float(v3.y & 0xFFFF0000u);
    }
    for (; e < eend; ++e) {
        int s = csr[e];
        uint2 v = xp[(size_t)s * 32 + lc];
        ax += __uint_as_float(v.x << 16);
        ay += __uint_as_float(v.x & 0xFFFF0000u);
        az += __uint_as_float(v.y << 16);
        aw += __uint_as_float(v.y & 0xFFFF0000u);
    }

    float4 o;
    o.x = di * ax; o.y = di * ay; o.z = di * az; o.w = di * aw;
    if (HAS_BIAS) {
        float4 bb = reinterpret_cast<const float4*>(bias)[lc];
        o.x += bb.x; o.y += bb.y; o.z += bb.z; o.w += bb.w;
    }
    if (RELU) {
        o.x = fmaxf(o.x, 0.0f); o.y = fmaxf(o.y, 0.0f);
        o.z = fmaxf(o.z, 0.0f); o.w = fmaxf(o.w, 0.0f);
    }
    reinterpret_cast<float4*>(out)[(size_t)node * 32 + lc] = o;
}

// ---------------------------------------------------------------------------
// Fused 2-GEMM chain (round-8 structure). New: BF16_OUT epilogue writes
// bf16_rne(dscale[r] * accQ) as packed bf16 rows (for prop2's gather).
// ---------------------------------------------------------------------------

template <int NHALF, int ACT1, bool FINAL_BIAS, bool BF16_OUT>
__global__ __launch_bounds__(256) void k_fused(
        const float* __restrict__ A,
        const u32* __restrict__ ftabW1,
        const u32* __restrict__ ftabW2,
        const float* __restrict__ b1v,
        const float* __restrict__ b2v,
        float* __restrict__ C,
        u32* __restrict__ C16,
        const float* __restrict__ dscale,
        int M) {
    __shared__ u32 lds_w[2][4096];   // 2 x 16 KB kf-batches

    const int tid = threadIdx.x;
    const int wave = tid >> 6, l = tid & 63;
    const int l15 = l & 15, l4 = l >> 4;
    const int r = blockIdx.x * 64 + wave * 16 + l15;
    const float* arow = A + (size_t)(r < M ? r : M - 1) * 128;

    const int NSTEP = NHALF * 8;

    auto stepbase = [&](int s) -> const u32* {
        int half = (NHALF == 2) ? (s >> 3) : 0;
        int phase = (s >> 2) & 1;
        int kf = s & 3;
        const u32* sec = phase ? ftabW2 : ftabW1;
        return sec + (size_t)half * 16384 + kf * 4096;
    };
    auto stage_batch = [&](int s, int buf) {
        const u32* g = stepbase(s) + wave * 1024 + 4 * l;
        u32* lb = &lds_w[buf][wave * 1024];
        stage16(g, lb);
        stage16(g + 256, lb + 256);
        stage16(g + 512, lb + 512);
        stage16(g + 768, lb + 768);
    };

    f32x4 accQ[8] = {};
    int buf = 0;

    stage_batch(0, 0);
    __syncthreads();

    for (int half = 0; half < NHALF; ++half) {
        // ---------------- phase 1: accH = W1h^T · A^T ----------------
        f32x4 accH[8] = {};
#pragma unroll
        for (int kf = 0; kf < 4; ++kf) {
            int s = half * 8 + kf;
            if (s + 1 < NSTEP) stage_batch(s + 1, buf ^ 1);

            const float* ap = arow + kf * 32 + l4 * 8;
            float4 v0 = *reinterpret_cast<const float4*>(ap);
            float4 v1 = *reinterpret_cast<const float4*>(ap + 4);
            float av[8] = {v0.x, v0.y, v0.z, v0.w, v1.x, v1.y, v1.z, v1.w};
            u32 hp[4], lp[4];
#pragma unroll
            for (int p = 0; p < 4; ++p) {
                float a0 = av[2 * p], a1 = av[2 * p + 1];
                u32 h0 = __float_as_uint(a0) & 0xFFFF0000u;
                u32 h1 = __float_as_uint(a1) & 0xFFFF0000u;
                float q0 = a0 - __uint_as_float(h0);
                float q1 = a1 - __uint_as_float(h1);
                hp[p] = (h0 >> 16) | h1;
                lp[p] = ((__float_as_uint(q0) & 0xFFFF0000u) >> 16) |
                        (__float_as_uint(q1) & 0xFFFF0000u);
            }
            bf16x8 ahi = pack_bf16x8(hp[0], hp[1], hp[2], hp[3]);
            bf16x8 alo = pack_bf16x8(lp[0], lp[1], lp[2], lp[3]);

            const u32* lb = lds_w[buf];
#pragma unroll
            for (int nf = 0; nf < 8; ++nf) {
                const u32* fb = lb + nf * 512;
                bf16x8 whi = as_bf16x8(*reinterpret_cast<const uint4*>(fb + 4 * l));
                bf16x8 wlo = as_bf16x8(*reinterpret_cast<const uint4*>(fb + 256 + 4 * l));
                accH[nf] = __builtin_amdgcn_mfma_f32_16x16x32_bf16(whi, ahi, accH[nf], 0, 0, 0);
                accH[nf] = __builtin_amdgcn_mfma_f32_16x16x32_bf16(whi, alo, accH[nf], 0, 0, 0);
                accH[nf] = __builtin_amdgcn_mfma_f32_16x16x32_bf16(wlo, ahi, accH[nf], 0, 0, 0);
            }
            __syncthreads();
            buf ^= 1;
        }

        // ---- epilogue 1: bias + act, split-pack (hi | lo<<16) ----
        u32 hpk[8][4];
#pragma unroll
        for (int nf = 0; nf < 8; ++nf) {
            const float4 bb = *reinterpret_cast<const float4*>(
                b1v + half * 128 + nf * 16 + l4 * 4);
            const float bbv[4] = {bb.x, bb.y, bb.z, bb.w};
#pragma unroll
            for (int reg = 0; reg < 4; ++reg) {
                float v = accH[nf][reg] + bbv[reg];
                if (ACT1 == 1) v = fmaxf(v, 0.0f);
                else           v = v > 0.0f ? v : (expf(v) - 1.0f);
                u32 vh = __float_as_uint(v) & 0xFFFF0000u;
                float rr = v - __uint_as_float(vh);
                hpk[nf][reg] = (vh >> 16) | (__float_as_uint(rr) & 0xFFFF0000u);
            }
        }

        // ---------------- phase 2: accQ += W2h^T · H^T ----------------
#pragma unroll
        for (int kf = 0; kf < 4; ++kf) {
            int s = half * 8 + 4 + kf;
            if (s + 1 < NSTEP) stage_batch(s + 1, buf ^ 1);

            u32 got[8];
#pragma unroll
            for (int je = 0; je < 8; ++je) {
                int srcLane = ((l4 & 1) * 2 + (je >> 2)) * 16 + l15;
                u32 g0 = __shfl(hpk[2 * kf][je & 3], srcLane, 64);
                u32 g1 = __shfl(hpk[2 * kf + 1][je & 3], srcLane, 64);
                got[je] = (l4 & 2) ? g1 : g0;
            }
            u32 hh[4], gg[4];
#pragma unroll
            for (int p = 0; p < 4; ++p) {
                hh[p] = (got[2 * p] & 0xFFFFu) | (got[2 * p + 1] << 16);
                gg[p] = (got[2 * p] >> 16) | (got[2 * p + 1] & 0xFFFF0000u);
            }
            bf16x8 bh = pack_bf16x8(hh[0], hh[1], hh[2], hh[3]);
            bf16x8 bl = pack_bf16x8(gg[0], gg[1], gg[2], gg[3]);

            const u32* lb = lds_w[buf];
#pragma unroll
            for (int nf = 0; nf < 8; ++nf) {
                const u32* fb = lb + nf * 512;
                bf16x8 whi = as_bf16x8(*reinterpret_cast<const uint4*>(fb + 4 * l));
                bf16x8 wlo = as_bf16x8(*reinterpret_cast<const uint4*>(fb + 256 + 4 * l));
                accQ[nf] = __builtin_amdgcn_mfma_f32_16x16x32_bf16(whi, bh, accQ[nf], 0, 0, 0);
                accQ[nf] = __builtin_amdgcn_mfma_f32_16x16x32_bf16(whi, bl, accQ[nf], 0, 0, 0);
                accQ[nf] = __builtin_amdgcn_mfma_f32_16x16x32_bf16(wlo, bh, accQ[nf], 0, 0, 0);
            }
            __syncthreads();
            buf ^= 1;
        }
    }

    // ---- final epilogue ----
    if (r < M) {
        if (BF16_OUT) {
            float sc = dscale[r];
#pragma unroll
            for (int nf = 0; nf < 8; ++nf) {
                u32 w0 = rne_bf16(accQ[nf][0] * sc) | (rne_bf16(accQ[nf][1] * sc) << 16);
                u32 w1 = rne_bf16(accQ[nf][2] * sc) | (rne_bf16(accQ[nf][3] * sc) << 16);
                reinterpret_cast<uint2*>(C16)[(size_t)r * 32 + nf * 4 + l4] =
                    make_uint2(w0, w1);
            }
        } else {
#pragma unroll
            for (int nf = 0; nf < 8; ++nf) {
                float4 v;
                v.x = accQ[nf][0]; v.y = accQ[nf][1];
                v.z = accQ[nf][2]; v.w = accQ[nf][3];
                if (FINAL_BIAS) {
                    const float4 bb = *reinterpret_cast<const float4*>(b2v + nf * 16 + l4 * 4);
                    v.x += bb.x; v.y += bb.y; v.z += bb.z; v.w += bb.w;
                }
                *reinterpret_cast<float4*>(C + (size_t)r * 128 + nf * 16 + l4 * 4) = v;
            }
        }
    }
}

// ---------------------------------------------------------------------------
// launch
// ---------------------------------------------------------------------------

extern "C" void kernel_launch(void* const* d_in, const int* in_sizes, int n_in,
                              void* d_out, int out_size, void* d_ws, size_t ws_size,
                              hipStream_t stream) {
    const float* x    = (const float*)d_in[0];
    const int*   ei   = (const int*)d_in[1];   // int64 in reference -> int32 from harness
    const float* W1   = (const float*)d_in[2]; // [128,256]
    const float* b1   = (const float*)d_in[3];
    const float* W2   = (const float*)d_in[4]; // [256,128]
    const float* b2   = (const float*)d_in[5];
    const float* fcW1 = (const float*)d_in[6]; // [128,128]
    const float* fcb1 = (const float*)d_in[7];
    const float* fcW2 = (const float*)d_in[8]; // [128,128]
    const float* fcb2 = (const float*)d_in[9];
    float* out        = (float*)d_out;         // [N,128], also ping-pong scratch

    char* ws = (char*)d_ws;
    size_t off = 0;
    auto alloc = [&](size_t bytes) {
        void* p = ws + off;
        off += (bytes + 255) & ~(size_t)255;
        return p;
    };
    int*   counts  = (int*)alloc(N_NODES * sizeof(int));
    int*   cursor  = (int*)alloc(N_NODES * sizeof(int));
    int*   part    = (int*)alloc(N_NODES * sizeof(int));
    int*   bsum    = (int*)alloc(SCAN_BLOCKS * sizeof(int));
    int*   boff    = (int*)alloc(SCAN_BLOCKS * sizeof(int));
    int*   offsets = (int*)alloc((N_NODES + 1) * sizeof(int));
    int*   csr     = (int*)alloc(N_EDGES * sizeof(int));
    float* dinv    = (float*)alloc(N_NODES * sizeof(float));
    u32*   ftab    = (u32*)alloc((size_t)192 * 512 * sizeof(u32));
    u32*   xs      = (u32*)alloc((size_t)N_NODES * 128 * 2);   // bf16 features
    u32*   qs      = (u32*)alloc((size_t)N_NODES * 128 * 2);   // bf16 mid output
    (void)ws_size; (void)n_in; (void)in_sizes; (void)out_size;

    const u32 SEC = 16384;  // u32 per 64 KB section

    // graph preprocessing + weight prep
    k_zero<<<(N_NODES + 255) / 256, 256, 0, stream>>>(counts, cursor, N_NODES);
    k_prep<<<192, 64, 0, stream>>>(W1, W2, fcW1, fcW2, ftab);
    k_count<<<(N_EDGES + 255) / 256, 256, 0, stream>>>(ei, counts);
    k_dinv<<<(N_NODES + 255) / 256, 256, 0, stream>>>(counts, dinv);
    k_xscale<<<(N_NODES * 32 + 255) / 256, 256, 0, stream>>>(x, dinv, xs);
    k_scan1<<<SCAN_BLOCKS, 256, 0, stream>>>(counts, part, bsum);
    k_scan2<<<1, 256, 0, stream>>>(bsum, boff);
    k_scan3<<<SCAN_BLOCKS, 256, 0, stream>>>(part, counts, boff, offsets);
    k_fill<<<(N_EDGES + 255) / 256, 256, 0, stream>>>(ei, offsets, cursor, csr);

    const int prop_grid = (N_NODES + 7) / 8;  // 6250: 8 nodes/block, 2 per wave
    const int gm = (N_NODES + 63) / 64;       // 782 (64 rows per block, 16 per wave)

    // layer 1 propagate: agg = dinv*(sum xs + xs_self) -> out (f32 scratch)
    k_prop<false, false><<<prop_grid, 256, 0, stream>>>(xs, out, dinv, offsets, csr, nullptr);

    // fused mid: qs = bf16( dinv * (relu(agg@W1 + b1) @ W2) )
    k_fused<2, 1, false, true><<<gm, 256, 0, stream>>>(out, ftab, ftab + 2 * SEC,
                                                       b1, nullptr, nullptr, qs, dinv, N_NODES);

    // layer 2 propagate: z = relu( dinv*(sum qs + qs_self) + b2 ) -> out
    k_prop<true, true><<<prop_grid, 256, 0, stream>>>(qs, out, dinv, offsets, csr, b2);

    // fused head (in-place): out = elu(out@fcW1 + fcb1) @ fcW2 + fcb2
    k_fused<1, 2, true, false><<<gm, 256, 0, stream>>>(out, ftab + 4 * SEC, ftab + 5 * SEC,
                                                       fcb1, fcb2, out, nullptr, nullptr, N_NODES);
}

// Round 11
// 226.747 us; speedup vs baseline: 2.0500x; 1.0586x over previous
//
#include <hip/hip_runtime.h>
#include <hip/hip_bf16.h>
#include <cstdint>

#define N_NODES 50000
#define N_EDGES 800000
#define C128 128
#define SCAN_BLOCKS ((N_NODES + 255) / 256)   // 196

typedef __attribute__((ext_vector_type(8))) short bf16x8;
typedef __attribute__((ext_vector_type(4))) float f32x4;
typedef unsigned int u32;

__device__ __forceinline__ bf16x8 pack_bf16x8(u32 a, u32 b, u32 c, u32 d) {
    union { u32 u[4]; bf16x8 v; } x;
    x.u[0] = a; x.u[1] = b; x.u[2] = c; x.u[3] = d;
    return x.v;
}

__device__ __forceinline__ bf16x8 as_bf16x8(uint4 v) {
    union { uint4 u; bf16x8 b; } x;
    x.u = v;
    return x.b;
}

// round-to-nearest-even f32 -> bf16 (returned in low 16 bits)
__device__ __forceinline__ u32 rne_bf16(float x) {
    u32 u = __float_as_uint(x);
    return (u + 0x7FFFu + ((u >> 16) & 1u)) >> 16;
}

// async global->LDS, 16B per lane: lds dest = base + lane*16, g is per-lane.
__device__ __forceinline__ void stage16(const u32* g, u32* lds) {
    __builtin_amdgcn_global_load_lds(
        (const __attribute__((address_space(1))) u32*)g,
        (__attribute__((address_space(3))) u32*)lds, 16, 0, 0);
}

// ---------------------------------------------------------------------------
// init / graph preprocessing
// ---------------------------------------------------------------------------

__global__ void k_zero(int* __restrict__ a, int* __restrict__ b, int n) {
    int i = blockIdx.x * blockDim.x + threadIdx.x;
    if (i < n) { a[i] = 0; b[i] = 0; }
}

__device__ __forceinline__ int clamp_node(int v) {
    return v < 0 ? 0 : (v >= N_NODES ? N_NODES - 1 : v);
}

__global__ void k_count(const int* __restrict__ ei, int* __restrict__ counts) {
    int e = blockIdx.x * blockDim.x + threadIdx.x;
    if (e < N_EDGES) {
        int dst = clamp_node(ei[N_EDGES + e]);
        atomicAdd(&counts[dst], 1);
    }
}

__global__ void k_dinv(const int* __restrict__ counts, float* __restrict__ dinv) {
    int i = blockIdx.x * blockDim.x + threadIdx.x;
    if (i < N_NODES) {
        dinv[i] = rsqrtf((float)counts[i] + 1.0f);
    }
}

// xs[i][c] = bf16_rne( dinv[i] * x[i][c] ), 4 channels per thread
__global__ __launch_bounds__(256) void k_xscale(const float* __restrict__ x,
                                                const float* __restrict__ dinv,
                                                u32* __restrict__ xs /*uint2 area*/) {
    int idx = blockIdx.x * 256 + threadIdx.x;      // one float4 group
    if (idx < N_NODES * 32) {
        int node = idx >> 5;
        float di = dinv[node];
        float4 v = reinterpret_cast<const float4*>(x)[idx];
        u32 w0 = rne_bf16(v.x * di) | (rne_bf16(v.y * di) << 16);
        u32 w1 = rne_bf16(v.z * di) | (rne_bf16(v.w * di) << 16);
        reinterpret_cast<uint2*>(xs)[idx] = make_uint2(w0, w1);
    }
}

__global__ __launch_bounds__(256) void k_scan1(const int* __restrict__ counts,
                                               int* __restrict__ part,
                                               int* __restrict__ bsum) {
    __shared__ int s[256];
    const int tid = threadIdx.x;
    const int i = blockIdx.x * 256 + tid;
    int v = (i < N_NODES) ? counts[i] : 0;
    s[tid] = v;
    __syncthreads();
    for (int off = 1; off < 256; off <<= 1) {
        int t = (tid >= off) ? s[tid - off] : 0;
        __syncthreads();
        s[tid] += t;
        __syncthreads();
    }
    if (i < N_NODES) part[i] = s[tid];
    if (tid == 255) bsum[blockIdx.x] = s[255];
}

__global__ __launch_bounds__(256) void k_scan2(const int* __restrict__ bsum,
                                               int* __restrict__ boff) {
    __shared__ int s[256];
    const int tid = threadIdx.x;
    int v = (tid < SCAN_BLOCKS) ? bsum[tid] : 0;
    s[tid] = v;
    __syncthreads();
    for (int off = 1; off < 256; off <<= 1) {
        int t = (tid >= off) ? s[tid - off] : 0;
        __syncthreads();
        s[tid] += t;
        __syncthreads();
    }
    if (tid < SCAN_BLOCKS) boff[tid] = s[tid] - v;
}

__global__ __launch_bounds__(256) void k_scan3(const int* __restrict__ part,
                                               const int* __restrict__ counts,
                                               const int* __restrict__ boff,
                                               int* __restrict__ offsets) {
    const int i = blockIdx.x * 256 + threadIdx.x;
    if (i < N_NODES) offsets[i] = part[i] - counts[i] + boff[blockIdx.x];
    if (i == 0) offsets[N_NODES] = N_EDGES;
}

__global__ void k_fill(const int* __restrict__ ei, const int* __restrict__ offsets,
                       int* __restrict__ cursor, int* __restrict__ csr) {
    int e = blockIdx.x * blockDim.x + threadIdx.x;
    if (e < N_EDGES) {
        int src = clamp_node(ei[e]);
        int dst = clamp_node(ei[N_EDGES + e]);
        int pos = atomicAdd(&cursor[dst], 1);
        int slot = offsets[dst] + pos;
        if (slot < N_EDGES) csr[slot] = src;
    }
}

// ---------------------------------------------------------------------------
// Weight prep (unchanged): frag f = kf*8+nf at section*16384 + f*512 u32;
// hi uint4 of lane l at +4l, lo at +256+4l.
// Sections: 0,1 = W1 halves; 2,3 = W2 halves; 4 = fcW1; 5 = fcW2.
// ---------------------------------------------------------------------------

__global__ __launch_bounds__(64) void k_prep(const float* __restrict__ W1,
                                             const float* __restrict__ W2,
                                             const float* __restrict__ fcW1,
                                             const float* __restrict__ fcW2,
                                             u32* __restrict__ ftab) {
    int bx = blockIdx.x;          // 0..191
    int s = bx >> 5, f = bx & 31;
    int kf = f >> 3, nf = f & 7;
    int l = threadIdx.x;
    const float* src; int ld, roff, coff;
    switch (s) {
        case 0:  src = W1;   ld = 256; roff = 0;   coff = 0;   break;
        case 1:  src = W1;   ld = 256; roff = 0;   coff = 128; break;
        case 2:  src = W2;   ld = 128; roff = 0;   coff = 0;   break;
        case 3:  src = W2;   ld = 128; roff = 128; coff = 0;   break;
        case 4:  src = fcW1; ld = 128; roff = 0;   coff = 0;   break;
        default: src = fcW2; ld = 128; roff = 0;   coff = 0;   break;
    }
    int col = coff + nf * 16 + (l & 15);
    int krow = roff + kf * 32 + (l >> 4) * 8;
    u32 hp[4], lp[4];
#pragma unroll
    for (int p = 0; p < 4; ++p) {
        float a0 = src[(size_t)(krow + 2 * p) * ld + col];
        float a1 = src[(size_t)(krow + 2 * p + 1) * ld + col];
        u32 h0 = __float_as_uint(a0) & 0xFFFF0000u;
        u32 h1 = __float_as_uint(a1) & 0xFFFF0000u;
        float r0 = a0 - __uint_as_float(h0);
        float r1 = a1 - __uint_as_float(h1);
        hp[p] = (h0 >> 16) | h1;
        lp[p] = ((__float_as_uint(r0) & 0xFFFF0000u) >> 16) |
                (__float_as_uint(r1) & 0xFFFF0000u);
    }
    u32* dst = ftab + ((size_t)(bx >> 5)) * 16384 + (size_t)(f) * 512;
    *reinterpret_cast<uint4*>(dst + 4 * l)       = make_uint4(hp[0], hp[1], hp[2], hp[3]);
    *reinterpret_cast<uint4*>(dst + 256 + 4 * l) = make_uint4(lp[0], lp[1], lp[2], lp[3]);
}

// ---------------------------------------------------------------------------
// Propagation over pre-scaled bf16 features (unchanged from round 10)
// ---------------------------------------------------------------------------

template <bool HAS_BIAS, bool RELU>
__global__ __launch_bounds__(256) void k_prop(const u32* __restrict__ xs,
                                              float* __restrict__ out,
                                              const float* __restrict__ dinv,
                                              const int* __restrict__ offsets,
                                              const int* __restrict__ csr,
                                              const float* __restrict__ bias) {
    const int wave = threadIdx.x >> 6;
    const int lane = threadIdx.x & 63;
    const int half = lane >> 5;
    const int lc   = lane & 31;          // 4-channel group
    const int node = (blockIdx.x * 4 + wave) * 2 + half;
    if (node >= N_NODES) return;

    const uint2* __restrict__ xp = reinterpret_cast<const uint2*>(xs);
    const float di = dinv[node];

    uint2 sv = xp[(size_t)node * 32 + lc];
    float ax = __uint_as_float(sv.x << 16);
    float ay = __uint_as_float(sv.x & 0xFFFF0000u);
    float az = __uint_as_float(sv.y << 16);
    float aw = __uint_as_float(sv.y & 0xFFFF0000u);

    int e = offsets[node];
    const int eend = offsets[node + 1];
    for (; e + 4 <= eend; e += 4) {
        int s0 = csr[e + 0], s1 = csr[e + 1], s2 = csr[e + 2], s3 = csr[e + 3];
        uint2 v0 = xp[(size_t)s0 * 32 + lc];
        uint2 v1 = xp[(size_t)s1 * 32 + lc];
        uint2 v2 = xp[(size_t)s2 * 32 + lc];
        uint2 v3 = xp[(size_t)s3 * 32 + lc];
        ax += __uint_as_float(v0.x << 16);
        ay += __uint_as_float(v0.x & 0xFFFF0000u);
        az += __uint_as_float(v0.y << 16);
        aw += __uint_as_float(v0.y & 0xFFFF0000u);
        ax += __uint_as_float(v1.x << 16);
        ay += __uint_as_float(v1.x & 0xFFFF0000u);
        az += __uint_as_float(v1.y << 16);
        aw += __uint_as_float(v1.y & 0xFFFF0000u);
        ax += __uint_as_float(v2.x << 16);
        ay += __uint_as_float(v2.x & 0xFFFF0000u);
        az += __uint_as_float(v2.y << 16);
        aw += __uint_as_float(v2.y & 0xFFFF0000u);
        ax += __uint_as_float(v3.x << 16);
        ay += __uint_as_float(v3.x & 0xFFFF0000u);
        az += __uint_as_float(v3.y << 16);
        aw += __uint_as_float(v3.y & 0xFFFF0000u);
    }
    for (; e < eend; ++e) {
        int s = csr[e];
        uint2 v = xp[(size_t)s * 32 + lc];
        ax += __uint_as_float(v.x << 16);
        ay += __uint_as_float(v.x & 0xFFFF0000u);
        az += __uint_as_float(v.y << 16);
        aw += __uint_as_float(v.y & 0xFFFF0000u);
    }

    float4 o;
    o.x = di * ax; o.y = di * ay; o.z = di * az; o.w = di * aw;
    if (HAS_BIAS) {
        float4 bb = reinterpret_cast<const float4*>(bias)[lc];
        o.x += bb.x; o.y += bb.y; o.z += bb.z; o.w += bb.w;
    }
    if (RELU) {
        o.x = fmaxf(o.x, 0.0f); o.y = fmaxf(o.y, 0.0f);
        o.z = fmaxf(o.z, 0.0f); o.w = fmaxf(o.w, 0.0f);
    }
    reinterpret_cast<float4*>(out)[(size_t)node * 32 + lc] = o;
}

// ---------------------------------------------------------------------------
// Fused 2-GEMM chain: per phase the FULL 64 KB weight section is LDS-resident.
//   stage(W1h) once -> barrier -> phase1 (no barriers: 32x{2 ds_read,6 MFMA})
//   -> barrier -> stage(W2h) overlapped with act/pack epilogue -> barrier
//   -> phase2 (no barriers) [-> barrier -> stage next half]
// 4 waves x 32 rows = 128 rows/block; grid 391; LDS 64 KB -> 2 blocks/CU.
// H^T fragments for phase2 built via 16-lane shuffles (validated r6-r10).
// ---------------------------------------------------------------------------

template <int NHALF, int ACT1, bool FINAL_BIAS, bool BF16_OUT>
__global__ __launch_bounds__(256, 2) void k_fused(
        const float* __restrict__ A,
        const u32* __restrict__ ftabW1,
        const u32* __restrict__ ftabW2,
        const float* __restrict__ b1v,
        const float* __restrict__ b2v,
        float* __restrict__ C,
        u32* __restrict__ C16,
        const float* __restrict__ dscale,
        int M) {
    __shared__ u32 lds_w[16384];   // 64 KB: one phase's weight section

    const int tid = threadIdx.x;
    const int wave = tid >> 6, l = tid & 63;
    const int l15 = l & 15, l4 = l >> 4;
    const int m_base = blockIdx.x * 128 + wave * 32;
    const int r0 = m_base + l15, r1 = m_base + 16 + l15;
    const float* arow0 = A + (size_t)(r0 < M ? r0 : M - 1) * 128;
    const float* arow1 = A + (size_t)(r1 < M ? r1 : M - 1) * 128;

    // stage a full 64 KB section: 16 x (per-wave 1 KB slices)
    auto stage_sec = [&](const u32* sec) {
#pragma unroll
        for (int i = 0; i < 16; ++i) {
            int off = i * 1024 + wave * 256;
            stage16(sec + off + 4 * l, lds_w + off);
        }
    };

    f32x4 accQ[2][8] = {};

    stage_sec(ftabW1);   // W1 half 0
    __syncthreads();

#pragma unroll
    for (int half = 0; half < NHALF; ++half) {
        // ---------------- phase 1: accH[t] = W1h^T · A[t]^T ----------------
        f32x4 accH[2][8] = {};
#pragma unroll
        for (int kf = 0; kf < 4; ++kf) {
            bf16x8 ahi[2], alo[2];
#pragma unroll
            for (int t = 0; t < 2; ++t) {
                const float* ap = (t == 0 ? arow0 : arow1) + kf * 32 + l4 * 8;
                float4 v0 = *reinterpret_cast<const float4*>(ap);
                float4 v1 = *reinterpret_cast<const float4*>(ap + 4);
                float av[8] = {v0.x, v0.y, v0.z, v0.w, v1.x, v1.y, v1.z, v1.w};
                u32 hp[4], lp[4];
#pragma unroll
                for (int p = 0; p < 4; ++p) {
                    float a0 = av[2 * p], a1 = av[2 * p + 1];
                    u32 h0 = __float_as_uint(a0) & 0xFFFF0000u;
                    u32 h1 = __float_as_uint(a1) & 0xFFFF0000u;
                    float q0 = a0 - __uint_as_float(h0);
                    float q1 = a1 - __uint_as_float(h1);
                    hp[p] = (h0 >> 16) | h1;
                    lp[p] = ((__float_as_uint(q0) & 0xFFFF0000u) >> 16) |
                            (__float_as_uint(q1) & 0xFFFF0000u);
                }
                ahi[t] = pack_bf16x8(hp[0], hp[1], hp[2], hp[3]);
                alo[t] = pack_bf16x8(lp[0], lp[1], lp[2], lp[3]);
            }
#pragma unroll
            for (int nf = 0; nf < 8; ++nf) {
                const u32* fb = lds_w + (kf * 8 + nf) * 512;
                bf16x8 whi = as_bf16x8(*reinterpret_cast<const uint4*>(fb + 4 * l));
                bf16x8 wlo = as_bf16x8(*reinterpret_cast<const uint4*>(fb + 256 + 4 * l));
#pragma unroll
                for (int t = 0; t < 2; ++t) {
                    accH[t][nf] = __builtin_amdgcn_mfma_f32_16x16x32_bf16(whi, ahi[t], accH[t][nf], 0, 0, 0);
                    accH[t][nf] = __builtin_amdgcn_mfma_f32_16x16x32_bf16(whi, alo[t], accH[t][nf], 0, 0, 0);
                    accH[t][nf] = __builtin_amdgcn_mfma_f32_16x16x32_bf16(wlo, ahi[t], accH[t][nf], 0, 0, 0);
                }
            }
        }
        __syncthreads();                         // everyone done reading W1h
        stage_sec(ftabW2 + (size_t)half * 16384);  // async stage W2h

        // ---- epilogue 1 (VALU, overlaps staging): bias+act, split-pack ----
        u32 hpk[2][8][4];
#pragma unroll
        for (int nf = 0; nf < 8; ++nf) {
            const float4 bb = *reinterpret_cast<const float4*>(
                b1v + half * 128 + nf * 16 + l4 * 4);
            const float bbv[4] = {bb.x, bb.y, bb.z, bb.w};
#pragma unroll
            for (int t = 0; t < 2; ++t) {
#pragma unroll
                for (int reg = 0; reg < 4; ++reg) {
                    float v = accH[t][nf][reg] + bbv[reg];
                    if (ACT1 == 1) v = fmaxf(v, 0.0f);
                    else           v = v > 0.0f ? v : (expf(v) - 1.0f);
                    u32 vh = __float_as_uint(v) & 0xFFFF0000u;
                    float rr = v - __uint_as_float(vh);
                    hpk[t][nf][reg] = (vh >> 16) | (__float_as_uint(rr) & 0xFFFF0000u);
                }
            }
        }
        __syncthreads();                         // W2h staged & visible

        // ---------------- phase 2: accQ[t] += W2h^T · H[t]^T ----------------
#pragma unroll
        for (int kf = 0; kf < 4; ++kf) {
            bf16x8 bh[2], bl[2];
#pragma unroll
            for (int t = 0; t < 2; ++t) {
                u32 got[8];
#pragma unroll
                for (int je = 0; je < 8; ++je) {
                    int srcLane = ((l4 & 1) * 2 + (je >> 2)) * 16 + l15;
                    u32 g0 = __shfl(hpk[t][2 * kf][je & 3], srcLane, 64);
                    u32 g1 = __shfl(hpk[t][2 * kf + 1][je & 3], srcLane, 64);
                    got[je] = (l4 & 2) ? g1 : g0;
                }
                u32 hh[4], gg[4];
#pragma unroll
                for (int p = 0; p < 4; ++p) {
                    hh[p] = (got[2 * p] & 0xFFFFu) | (got[2 * p + 1] << 16);
                    gg[p] = (got[2 * p] >> 16) | (got[2 * p + 1] & 0xFFFF0000u);
                }
                bh[t] = pack_bf16x8(hh[0], hh[1], hh[2], hh[3]);
                bl[t] = pack_bf16x8(gg[0], gg[1], gg[2], gg[3]);
            }
#pragma unroll
            for (int nf = 0; nf < 8; ++nf) {
                const u32* fb = lds_w + (kf * 8 + nf) * 512;
                bf16x8 whi = as_bf16x8(*reinterpret_cast<const uint4*>(fb + 4 * l));
                bf16x8 wlo = as_bf16x8(*reinterpret_cast<const uint4*>(fb + 256 + 4 * l));
#pragma unroll
                for (int t = 0; t < 2; ++t) {
                    accQ[t][nf] = __builtin_amdgcn_mfma_f32_16x16x32_bf16(whi, bh[t], accQ[t][nf], 0, 0, 0);
                    accQ[t][nf] = __builtin_amdgcn_mfma_f32_16x16x32_bf16(whi, bl[t], accQ[t][nf], 0, 0, 0);
                    accQ[t][nf] = __builtin_amdgcn_mfma_f32_16x16x32_bf16(wlo, bh[t], accQ[t][nf], 0, 0, 0);
                }
            }
        }

        if (half + 1 < NHALF) {
            __syncthreads();                     // done reading W2h
            stage_sec(ftabW1 + (size_t)(half + 1) * 16384);
            __syncthreads();                     // W1h(next) visible
        }
    }

    // ---- final epilogue ----
#pragma unroll
    for (int t = 0; t < 2; ++t) {
        int r = (t == 0) ? r0 : r1;
        if (r >= M) continue;
        if (BF16_OUT) {
            float sc = dscale[r];
#pragma unroll
            for (int nf = 0; nf < 8; ++nf) {
                u32 w0 = rne_bf16(accQ[t][nf][0] * sc) | (rne_bf16(accQ[t][nf][1] * sc) << 16);
                u32 w1 = rne_bf16(accQ[t][nf][2] * sc) | (rne_bf16(accQ[t][nf][3] * sc) << 16);
                reinterpret_cast<uint2*>(C16)[(size_t)r * 32 + nf * 4 + l4] =
                    make_uint2(w0, w1);
            }
        } else {
#pragma unroll
            for (int nf = 0; nf < 8; ++nf) {
                float4 v;
                v.x = accQ[t][nf][0]; v.y = accQ[t][nf][1];
                v.z = accQ[t][nf][2]; v.w = accQ[t][nf][3];
                if (FINAL_BIAS) {
                    const float4 bb = *reinterpret_cast<const float4*>(b2v + nf * 16 + l4 * 4);
                    v.x += bb.x; v.y += bb.y; v.z += bb.z; v.w += bb.w;
                }
                *reinterpret_cast<float4*>(C + (size_t)r * 128 + nf * 16 + l4 * 4) = v;
            }
        }
    }
}

// ---------------------------------------------------------------------------
// launch
// ---------------------------------------------------------------------------

extern "C" void kernel_launch(void* const* d_in, const int* in_sizes, int n_in,
                              void* d_out, int out_size, void* d_ws, size_t ws_size,
                              hipStream_t stream) {
    const float* x    = (const float*)d_in[0];
    const int*   ei   = (const int*)d_in[1];   // int64 in reference -> int32 from harness
    const float* W1   = (const float*)d_in[2]; // [128,256]
    const float* b1   = (const float*)d_in[3];
    const float* W2   = (const float*)d_in[4]; // [256,128]
    const float* b2   = (const float*)d_in[5];
    const float* fcW1 = (const float*)d_in[6]; // [128,128]
    const float* fcb1 = (const float*)d_in[7];
    const float* fcW2 = (const float*)d_in[8]; // [128,128]
    const float* fcb2 = (const float*)d_in[9];
    float* out        = (float*)d_out;         // [N,128], also ping-pong scratch

    char* ws = (char*)d_ws;
    size_t off = 0;
    auto alloc = [&](size_t bytes) {
        void* p = ws + off;
        off += (bytes + 255) & ~(size_t)255;
        return p;
    };
    int*   counts  = (int*)alloc(N_NODES * sizeof(int));
    int*   cursor  = (int*)alloc(N_NODES * sizeof(int));
    int*   part    = (int*)alloc(N_NODES * sizeof(int));
    int*   bsum    = (int*)alloc(SCAN_BLOCKS * sizeof(int));
    int*   boff    = (int*)alloc(SCAN_BLOCKS * sizeof(int));
    int*   offsets = (int*)alloc((N_NODES + 1) * sizeof(int));
    int*   csr     = (int*)alloc(N_EDGES * sizeof(int));
    float* dinv    = (float*)alloc(N_NODES * sizeof(float));
    u32*   ftab    = (u32*)alloc((size_t)6 * 16384 * sizeof(u32));
    u32*   xs      = (u32*)alloc((size_t)N_NODES * 128 * 2);   // bf16 features
    u32*   qs      = (u32*)alloc((size_t)N_NODES * 128 * 2);   // bf16 mid output
    (void)ws_size; (void)n_in; (void)in_sizes; (void)out_size;

    const u32 SEC = 16384;  // u32 per 64 KB section

    // graph preprocessing + weight prep
    k_zero<<<(N_NODES + 255) / 256, 256, 0, stream>>>(counts, cursor, N_NODES);
    k_prep<<<192, 64, 0, stream>>>(W1, W2, fcW1, fcW2, ftab);
    k_count<<<(N_EDGES + 255) / 256, 256, 0, stream>>>(ei, counts);
    k_dinv<<<(N_NODES + 255) / 256, 256, 0, stream>>>(counts, dinv);
    k_xscale<<<(N_NODES * 32 + 255) / 256, 256, 0, stream>>>(x, dinv, xs);
    k_scan1<<<SCAN_BLOCKS, 256, 0, stream>>>(counts, part, bsum);
    k_scan2<<<1, 256, 0, stream>>>(bsum, boff);
    k_scan3<<<SCAN_BLOCKS, 256, 0, stream>>>(part, counts, boff, offsets);
    k_fill<<<(N_EDGES + 255) / 256, 256, 0, stream>>>(ei, offsets, cursor, csr);

    const int prop_grid = (N_NODES + 7) / 8;  // 6250: 8 nodes/block, 2 per wave
    const int gm = (N_NODES + 127) / 128;     // 391 (128 rows/block, 32 per wave)

    // layer 1 propagate: agg = dinv*(sum xs + xs_self) -> out (f32 scratch)
    k_prop<false, false><<<prop_grid, 256, 0, stream>>>(xs, out, dinv, offsets, csr, nullptr);

    // fused mid: qs = bf16( dinv * (relu(agg@W1 + b1) @ W2) )
    k_fused<2, 1, false, true><<<gm, 256, 0, stream>>>(out, ftab, ftab + 2 * SEC,
                                                       b1, nullptr, nullptr, qs, dinv, N_NODES);

    // layer 2 propagate: z = relu( dinv*(sum qs + qs_self) + b2 ) -> out
    k_prop<true, true><<<prop_grid, 256, 0, stream>>>(qs, out, dinv, offsets, csr, b2);

    // fused head (in-place): out = elu(out@fcW1 + fcb1) @ fcW2 + fcb2
    k_fused<1, 2, true, false><<<gm, 256, 0, stream>>>(out, ftab + 4 * SEC, ftab + 5 * SEC,
                                                       fcb1, fcb2, out, nullptr, nullptr, N_NODES);
}